// Round 10
// baseline (187.684 us; speedup 1.0000x reference)
//
#include <hip/hip_runtime.h>

// GAT layer, N=4096, FIN=FOUT=256, H=1.
// cvt -> proj GEMM -> s_src/s_tgt -> score_exp (NT-load streaming map + in-wave
// rowsum atomics) -> split-K GEMM P@projT (BN=128, bf16 partials) -> reduce
// (NT partials, /Lrow, elu -> out0 NT + E) -> sim GEMM (E E^T) with fused
// sigmoid*aux epilogue AND fused row-stats (Bsum/Bsq block sums) ->
// stats_small (mean/rstd) -> finalize (NT t reads, NT upd stores).

using f32x4  = __attribute__((ext_vector_type(4))) float;
using bf16x8 = __attribute__((ext_vector_type(8))) __bf16;
using bf16x4 = __attribute__((ext_vector_type(4))) __bf16;
using u32x4  = __attribute__((ext_vector_type(4))) unsigned int;

__global__ __launch_bounds__(256) void cvt_nodes_kernel(const float* __restrict__ x,
                                                        __bf16* __restrict__ y) {
  int i = (blockIdx.x * 256 + threadIdx.x) * 4;
  f32x4 v = *(const f32x4*)(x + i);
  bf16x4 o = { (__bf16)v[0], (__bf16)v[1], (__bf16)v[2], (__bf16)v[3] };
  *(bf16x4*)(y + i) = o;
}

__global__ __launch_bounds__(256) void cvt_wt_kernel(const float* __restrict__ w,
                                                     __bf16* __restrict__ wt) {
  int i = blockIdx.x * 256 + threadIdx.x;
  int o = i >> 8, f = i & 255;
  wt[i] = (__bf16)w[f * 256 + o];
}

__global__ __launch_bounds__(256) void zero_kernel(float* __restrict__ p) {
  p[blockIdx.x * 256 + threadIdx.x] = 0.0f;
}

// Generic bf16 GEMM: C[m,n] = sum_k A[m,k] * Bt[n,k].
// MODE 0: write proj f32 [m*256+n], projT bf16 [n*4096+m]
// MODE 2: t = sigmoid(v)*(-e0)*(e1>0)+1e-6          (+ fused row stats)
// MODE 3: t = sigmoid(v)*(float)NT(axp)+1e-6        (+ fused row stats)
template<int BM, int BN, int MODE>
__global__ __launch_bounds__(256) void gemm_bf16_kernel(
    const __bf16* __restrict__ A, const __bf16* __restrict__ Bt,
    int M, int N, int K,
    float* __restrict__ outf, __bf16* __restrict__ outb,
    const float* __restrict__ e0, const float* __restrict__ e1,
    const __bf16* __restrict__ axp, float* __restrict__ outt,
    float* __restrict__ bsum, float* __restrict__ bsq)
{
  constexpr int LDT = 72;
  constexpr int MI = BM / 32;
  constexpr int NI = BN / 32;
  __shared__ alignas(16) __bf16 As[BM * LDT];
  __shared__ alignas(16) __bf16 Bs[BN * LDT];
  const int tid  = threadIdx.x;
  const int lane = tid & 63;
  const int wid  = tid >> 6;
  const int wm0  = (wid >> 1) * (BM / 2);
  const int wn0  = (wid & 1) * (BN / 2);
  const int m0   = blockIdx.x * BM;
  const int n0   = blockIdx.y * BN;
  const int lr   = lane & 15;
  const int lk   = lane >> 4;

  f32x4 acc[MI][NI];
#pragma unroll
  for (int a = 0; a < MI; ++a)
#pragma unroll
    for (int b = 0; b < NI; ++b) acc[a][b] = (f32x4){0.f, 0.f, 0.f, 0.f};

  for (int kt = 0; kt < K; kt += 64) {
    __syncthreads();
    for (int idx = tid; idx < BM * 8; idx += 256) {
      int r = idx >> 3, c = idx & 7;
      u32x4 v = *(const u32x4*)(A + (size_t)(m0 + r) * K + kt + c * 8);
      *(u32x4*)(As + r * LDT + c * 8) = v;
    }
    for (int idx = tid; idx < BN * 8; idx += 256) {
      int r = idx >> 3, c = idx & 7;
      u32x4 v = *(const u32x4*)(Bt + (size_t)(n0 + r) * K + kt + c * 8);
      *(u32x4*)(Bs + r * LDT + c * 8) = v;
    }
    __syncthreads();
#pragma unroll
    for (int kk = 0; kk < 2; ++kk) {
      bf16x8 av[MI], bv[NI];
#pragma unroll
      for (int mi = 0; mi < MI; ++mi)
        av[mi] = *(const bf16x8*)(As + (wm0 + mi * 16 + lr) * LDT + kk * 32 + lk * 8);
#pragma unroll
      for (int ni = 0; ni < NI; ++ni)
        bv[ni] = *(const bf16x8*)(Bs + (wn0 + ni * 16 + lr) * LDT + kk * 32 + lk * 8);
#pragma unroll
      for (int mi = 0; mi < MI; ++mi)
#pragma unroll
        for (int ni = 0; ni < NI; ++ni)
          acc[mi][ni] = __builtin_amdgcn_mfma_f32_16x16x32_bf16(av[mi], bv[ni], acc[mi][ni], 0, 0, 0);
    }
  }

  if constexpr (MODE == 0) {
#pragma unroll
    for (int mi = 0; mi < MI; ++mi)
#pragma unroll
      for (int ni = 0; ni < NI; ++ni)
#pragma unroll
        for (int j = 0; j < 4; ++j) {
          const int m = m0 + wm0 + mi * 16 + lk * 4 + j;
          const int n = n0 + wn0 + ni * 16 + lr;
          const float v = acc[mi][ni][j];
          outf[(size_t)m * 256 + n] = v;
          outb[(size_t)n * 4096 + m] = (__bf16)v;
        }
  } else {
    // epilogue + fused per-row stats (sum over this block's BN columns)
#pragma unroll
    for (int mi = 0; mi < MI; ++mi) {
#pragma unroll
      for (int j = 0; j < 4; ++j) {
        const int m = m0 + wm0 + mi * 16 + lk * 4 + j;
        float s = 0.f, s2 = 0.f;
#pragma unroll
        for (int ni = 0; ni < NI; ++ni) {
          const int n = n0 + wn0 + ni * 16 + lr;
          const size_t idx = (size_t)m * 4096 + n;
          const float v = acc[mi][ni][j];
          const float sg = 1.0f / (1.0f + __expf(-v));
          float tval;
          if constexpr (MODE == 2) {
            const float d = e0[idx];
            const float g = e1[idx];
            tval = sg * (-d) * (g > 0.f ? 1.0f : 0.0f) + 1e-6f;
          } else {
            const float a = (float)__builtin_nontemporal_load(axp + idx);
            tval = sg * a + 1e-6f;
          }
          outt[idx] = tval;
          s += tval;
          s2 += tval * tval;
        }
        // reduce across the 16 lanes (lr) sharing this row
#pragma unroll
        for (int o = 1; o < 16; o <<= 1) {
          s  += __shfl_xor(s, o, 64);
          s2 += __shfl_xor(s2, o, 64);
        }
        if (lr == 0) {
          const int slot = blockIdx.y * 2 + (wid & 1);   // 64 col-slots
          bsum[(size_t)slot * 4096 + m] = s;
          bsq [(size_t)slot * 4096 + m] = s2;
        }
      }
    }
  }
}

// mean/rstd from 64 column-block partial sums. grid 16 x 256.
__global__ __launch_bounds__(256) void stats_small_kernel(
    const float* __restrict__ bsum, const float* __restrict__ bsq,
    float* __restrict__ mean, float* __restrict__ rstd)
{
  const int row = blockIdx.x * 256 + threadIdx.x;
  float S = 0.f, S2 = 0.f;
#pragma unroll 8
  for (int s = 0; s < 64; ++s) {
    S  += bsum[(size_t)s * 4096 + row];
    S2 += bsq [(size_t)s * 4096 + row];
  }
  const float m  = S * (1.0f / 4096.0f);
  const float var = S2 * (1.0f / 4096.0f) - m * m;
  mean[row] = m;
  rstd[row] = rsqrtf(var + 1e-5f);
}

// NT-load streaming map + in-wave rowsum. dist/bond/deg single-use -> nt.
__global__ __launch_bounds__(256) void score_exp_kernel(
    const float* __restrict__ dist, const float* __restrict__ bond,
    const float* __restrict__ deg,  const float* __restrict__ ssrc,
    const float* __restrict__ stgt, const float* __restrict__ wdp,
    const float* __restrict__ wbp,  __bf16* __restrict__ P,
    __bf16* __restrict__ aux,       float* __restrict__ Lrow)
{
  const float wd = wdp[0], wb = wbp[0];
  const int lane = threadIdx.x & 63;
  size_t i = ((size_t)blockIdx.x * 256 + threadIdx.x) * 4;
  const size_t stride = (size_t)4096 * 256 * 4;
#pragma unroll 2
  for (int it = 0; it < 4; ++it, i += stride) {
    const int row = (int)(i >> 12);
    const int col = (int)(i & 4095);
    f32x4 d  = __builtin_nontemporal_load((const f32x4*)(dist + i));
    f32x4 g  = __builtin_nontemporal_load((const f32x4*)(deg + i));
    f32x4 b  = __builtin_nontemporal_load((const f32x4*)(bond + i));
    f32x4 st = *(const f32x4*)(stgt + col);
    const float si = ssrc[row];
    f32x4 p;
    bf16x4 pb, ab;
#pragma unroll
    for (int q = 0; q < 4; ++q) {
      float x = si + st[q];
      x = x > 0.f ? x : 0.2f * x;
      x += -d[q] * wd + b[q] * wb + (g[q] > 0.f ? g[q] : -1000000.0f);
      p[q] = __expf(x);
      pb[q] = (__bf16)p[q];
      ab[q] = (__bf16)(g[q] > 0.f ? -d[q] : 0.0f);
    }
    *(bf16x4*)(P + i) = pb;
    if (aux) *(bf16x4*)(aux + i) = ab;
    float s = p[0] + p[1] + p[2] + p[3];
#pragma unroll
    for (int o = 32; o; o >>= 1) s += __shfl_xor(s, o, 64);
    if (lane == 0) atomicAdd(Lrow + row, s);   // whole wave is in one row
  }
}

// split-K GEMM: partial[s][m*256+n] (bf16), BM=64 BN=128, K-chunk 512.
// grid (64, 2, 8), 256 threads (4 waves: 2m x 2n, each 32m x 64n).
__global__ __launch_bounds__(256) void gemm_splitk_kernel(
    const __bf16* __restrict__ A, const __bf16* __restrict__ Bt,
    __bf16* __restrict__ partial)
{
  constexpr int LDT = 72;
  __shared__ alignas(16) __bf16 As[64 * LDT];
  __shared__ alignas(16) __bf16 Bs[128 * LDT];
  const int tid  = threadIdx.x;
  const int lane = tid & 63;
  const int wid  = tid >> 6;
  const int wm0  = (wid >> 1) * 32;
  const int wn0  = (wid & 1) * 64;
  const int m0   = blockIdx.x * 64;
  const int n0   = blockIdx.y * 128;
  const int s    = blockIdx.z;
  const int lr   = lane & 15;
  const int lk   = lane >> 4;

  f32x4 acc[2][4];
#pragma unroll
  for (int a = 0; a < 2; ++a)
#pragma unroll
    for (int b = 0; b < 4; ++b) acc[a][b] = (f32x4){0.f, 0.f, 0.f, 0.f};

  const int k0 = s * 512;
  for (int kt = k0; kt < k0 + 512; kt += 64) {
    __syncthreads();
    for (int idx = tid; idx < 512; idx += 256) {
      int r = idx >> 3, c = idx & 7;
      u32x4 v = *(const u32x4*)(A + (size_t)(m0 + r) * 4096 + kt + c * 8);
      *(u32x4*)(As + r * LDT + c * 8) = v;
    }
    for (int idx = tid; idx < 1024; idx += 256) {
      int r = idx >> 3, c = idx & 7;
      u32x4 v = *(const u32x4*)(Bt + (size_t)(n0 + r) * 4096 + kt + c * 8);
      *(u32x4*)(Bs + r * LDT + c * 8) = v;
    }
    __syncthreads();
#pragma unroll
    for (int kk = 0; kk < 2; ++kk) {
      bf16x8 av[2], bv[4];
#pragma unroll
      for (int mi = 0; mi < 2; ++mi)
        av[mi] = *(const bf16x8*)(As + (wm0 + mi * 16 + lr) * LDT + kk * 32 + lk * 8);
#pragma unroll
      for (int ni = 0; ni < 4; ++ni)
        bv[ni] = *(const bf16x8*)(Bs + (wn0 + ni * 16 + lr) * LDT + kk * 32 + lk * 8);
#pragma unroll
      for (int mi = 0; mi < 2; ++mi)
#pragma unroll
        for (int ni = 0; ni < 4; ++ni)
          acc[mi][ni] = __builtin_amdgcn_mfma_f32_16x16x32_bf16(av[mi], bv[ni], acc[mi][ni], 0, 0, 0);
    }
  }

  __bf16* Pp = partial + (size_t)s * (4096 * 256);
#pragma unroll
  for (int mi = 0; mi < 2; ++mi)
#pragma unroll
    for (int ni = 0; ni < 4; ++ni)
#pragma unroll
      for (int j = 0; j < 4; ++j) {
        const int m = m0 + wm0 + mi * 16 + lk * 4 + j;
        const int n = n0 + wn0 + ni * 16 + lr;
        Pp[(size_t)m * 256 + n] = (__bf16)acc[mi][ni][j];
      }
}

// sum 8 bf16 partials (NT), /Lrow, elu -> out0 (NT store) + E (bf16).
__global__ __launch_bounds__(256) void reduce_elu_kernel(
    const __bf16* __restrict__ partial, const float* __restrict__ Lrow,
    float* __restrict__ out0, __bf16* __restrict__ E)
{
  __shared__ float tile[64][65];
  __shared__ float invL[64];
  const int tid = threadIdx.x;
  const int m0 = blockIdx.x * 64;
  const int f0 = blockIdx.y * 64;
  if (tid < 64) invL[tid] = 1.0f / Lrow[m0 + tid];
  f32x4 accv[4];
#pragma unroll
  for (int i = 0; i < 4; ++i) {
    int lin = i * 1024 + tid * 4;
    int r = lin >> 6, c = lin & 63;
    f32x4 sum = (f32x4){0.f, 0.f, 0.f, 0.f};
#pragma unroll
    for (int s = 0; s < 8; ++s) {
      bf16x4 pv = __builtin_nontemporal_load(
          (const bf16x4*)(partial + (size_t)s * (4096 * 256) +
                          (size_t)(m0 + r) * 256 + f0 + c));
#pragma unroll
      for (int q = 0; q < 4; ++q) sum[q] += (float)pv[q];
    }
    accv[i] = sum;
  }
  __syncthreads();   // invL ready
#pragma unroll
  for (int i = 0; i < 4; ++i) {
    int lin = i * 1024 + tid * 4;
    int r = lin >> 6, c = lin & 63;
    const float inv = invL[r];
    tile[r][c]     = accv[i][0] * inv;
    tile[r][c + 1] = accv[i][1] * inv;
    tile[r][c + 2] = accv[i][2] * inv;
    tile[r][c + 3] = accv[i][3] * inv;
  }
  __syncthreads();
#pragma unroll
  for (int i = 0; i < 4; ++i) {
    int lin = i * 1024 + tid * 4;
    int rr = lin >> 6, cc = lin & 63;   // rr: feature offset, cc: node offset
    f32x4 e;
#pragma unroll
    for (int q = 0; q < 4; ++q) {
      float v = tile[cc + q][rr];
      e[q] = v > 0.f ? v : expm1f(v);
    }
    size_t idx = (size_t)(f0 + rr) * 4096 + m0 + cc;
    __builtin_nontemporal_store(e, (f32x4*)(out0 + idx));
    bf16x4 eb = { (__bf16)e[0], (__bf16)e[1], (__bf16)e[2], (__bf16)e[3] };
    *(bf16x4*)(E + idx) = eb;
  }
}

// s_src[n] = proj[n,:].a_src ; s_tgt[n] = proj[n,:].a_tgt
__global__ __launch_bounds__(256) void sproj_kernel(const float* __restrict__ proj,
                                                    const float* __restrict__ asrc,
                                                    const float* __restrict__ atgt,
                                                    float* __restrict__ ssrc,
                                                    float* __restrict__ stgt) {
  const int row  = blockIdx.x * 4 + (threadIdx.x >> 6);
  const int lane = threadIdx.x & 63;
  f32x4 p = *(const f32x4*)(proj + (size_t)row * 256 + lane * 4);
  f32x4 a = *(const f32x4*)(asrc + lane * 4);
  f32x4 b = *(const f32x4*)(atgt + lane * 4);
  float d1 = p[0]*a[0] + p[1]*a[1] + p[2]*a[2] + p[3]*a[3];
  float d2 = p[0]*b[0] + p[1]*b[1] + p[2]*b[2] + p[3]*b[3];
#pragma unroll
  for (int o = 32; o; o >>= 1) { d1 += __shfl_xor(d1, o, 64); d2 += __shfl_xor(d2, o, 64); }
  if (lane == 0) { ssrc[row] = d1; stgt[row] = d2; }
}

// in-place: t[i,j] <- (t[i,j]-mean_i)*rstd_i + (t[j,i]-mean_j)*rstd_j
// t reads are single-use (NT); final writes never re-read (NT stores).
__global__ __launch_bounds__(256) void finalize_kernel(float* __restrict__ t,
                                                       const float* __restrict__ mean,
                                                       const float* __restrict__ rstd) {
  const int bj = blockIdx.x, bi = blockIdx.y;
  if (bi > bj) return;
  __shared__ float ta[64][65];
  __shared__ float tb[64][65];
  const int tid = threadIdx.x;
#pragma unroll
  for (int i = 0; i < 4; ++i) {
    int lin = i * 1024 + tid * 4;
    int r = lin >> 6, c = lin & 63;
    f32x4 va = __builtin_nontemporal_load(
        (const f32x4*)(t + (size_t)(bi * 64 + r) * 4096 + bj * 64 + c));
    ta[r][c] = va[0]; ta[r][c+1] = va[1]; ta[r][c+2] = va[2]; ta[r][c+3] = va[3];
  }
  if (bi != bj) {
#pragma unroll
    for (int i = 0; i < 4; ++i) {
      int lin = i * 1024 + tid * 4;
      int r = lin >> 6, c = lin & 63;
      f32x4 vb = __builtin_nontemporal_load(
          (const f32x4*)(t + (size_t)(bj * 64 + r) * 4096 + bi * 64 + c));
      tb[r][c] = vb[0]; tb[r][c+1] = vb[1]; tb[r][c+2] = vb[2]; tb[r][c+3] = vb[3];
    }
  }
  __syncthreads();
#pragma unroll
  for (int i = 0; i < 4; ++i) {
    int lin = i * 1024 + tid * 4;
    int r = lin >> 6, c = lin & 63;
    int gi = bi * 64 + r, gj = bj * 64 + c;
    const float mi_ = mean[gi], ri_ = rstd[gi];
    f32x4 mj = *(const f32x4*)(mean + gj);
    f32x4 rj = *(const f32x4*)(rstd + gj);
    f32x4 o;
#pragma unroll
    for (int q = 0; q < 4; ++q) {
      float v = (ta[r][c + q] - mi_) * ri_;
      float w = (bi == bj) ? (ta[c + q][r] - mj[q]) * rj[q]
                           : (tb[c + q][r] - mj[q]) * rj[q];
      o[q] = v + w;
    }
    __builtin_nontemporal_store(o, (f32x4*)(t + (size_t)gi * 4096 + gj));
  }
  if (bi != bj) {
#pragma unroll
    for (int i = 0; i < 4; ++i) {
      int lin = i * 1024 + tid * 4;
      int r = lin >> 6, c = lin & 63;
      int gi = bj * 64 + r, gj = bi * 64 + c;
      const float mi_ = mean[gi], ri_ = rstd[gi];
      f32x4 mj = *(const f32x4*)(mean + gj);
      f32x4 rj = *(const f32x4*)(rstd + gj);
      f32x4 o;
#pragma unroll
      for (int q = 0; q < 4; ++q) {
        float v = (tb[r][c + q] - mi_) * ri_;
        float w = (ta[c + q][r] - mj[q]) * rj[q];
        o[q] = v + w;
      }
      __builtin_nontemporal_store(o, (f32x4*)(t + (size_t)gi * 4096 + gj));
    }
  }
}

extern "C" void kernel_launch(void* const* d_in, const int* in_sizes, int n_in,
                              void* d_out, int out_size, void* d_ws, size_t ws_size,
                              hipStream_t stream) {
  const float* nodes  = (const float*)d_in[0];
  const float* degree = (const float*)d_in[1];
  const float* dist   = (const float*)d_in[2];
  const float* bond   = (const float*)d_in[3];
  const float* W      = (const float*)d_in[4];
  const float* a_src  = (const float*)d_in[5];
  const float* a_tgt  = (const float*)d_in[6];
  const float* w_dist = (const float*)d_in[7];
  const float* w_bond = (const float*)d_in[8];

  char* ws = (char*)d_ws;
  __bf16* nodesB = (__bf16*)ws;                                  // 2 MB
  __bf16* Wt     = (__bf16*)(ws + (2u << 20));                   // 128 KB
  __bf16* projT  = (__bf16*)(ws + (2u << 20) + (256u << 10));    // 2 MB
  float*  proj   = (float*)(ws + (5u << 20));                    // 4 MB
  __bf16* E      = (__bf16*)(ws + (9u << 20));                   // 2 MB
  float*  ssrc   = (float*)(ws + (11u << 20));                   // 16 KB
  float*  stgt   = ssrc + 4096;
  float*  mean   = stgt + 4096;
  float*  rstd   = mean + 4096;
  float*  Lrow   = rstd + 4096;                                  // 16 KB

  // aux (32 MB at +12 MB) + Bsum/Bsq (2 MB at +44 MB) need ws >= 48 MB.
  const bool useAux = ws_size >= (size_t)(48u << 20);
  __bf16* aux  = useAux ? (__bf16*)(ws + (12u << 20)) : nullptr;
  float* Bsum  = useAux ? (float*)(ws + (44u << 20))
                        : (float*)(ws + (12u << 20));
  float* Bsq   = Bsum + (size_t)64 * 4096;

  float*  out0 = (float*)d_out;                 // 4096*256 f32 (output 0)
  float*  t    = out0 + (size_t)4096 * 256;     // 4096*4096 f32 (output 1 region)
  __bf16* P    = (__bf16*)t;                    // exp-scores bf16: lower 32 MiB
  __bf16* partials = (__bf16*)((char*)t + ((size_t)32 << 20)); // 8 x 2 MB bf16

  cvt_nodes_kernel<<<1024, 256, 0, stream>>>(nodes, nodesB);
  cvt_wt_kernel<<<256, 256, 0, stream>>>(W, Wt);

  // proj = nodes @ W   (M=4096, N=256, K=256)
  gemm_bf16_kernel<64, 64, 0><<<dim3(64, 4), 256, 0, stream>>>(
      nodesB, Wt, 4096, 256, 256, proj, projT,
      nullptr, nullptr, nullptr, nullptr, nullptr, nullptr);

  sproj_kernel<<<1024, 256, 0, stream>>>(proj, a_src, a_tgt, ssrc, stgt);

  zero_kernel<<<16, 256, 0, stream>>>(Lrow);

  // P = exp(scores), aux, Lrow — NT-load streaming map
  score_exp_kernel<<<4096, 256, 0, stream>>>(dist, bond, degree, ssrc, stgt,
                                             w_dist, w_bond, P, aux, Lrow);

  // agg-partials (bf16) = P @ projT, split-K over 8 chunks of 512
  gemm_splitk_kernel<<<dim3(64, 2, 8), 256, 0, stream>>>(P, projT, partials);

  // sum partials, /Lrow, elu -> out0 (f32, transposed, NT) + E (bf16)
  reduce_elu_kernel<<<dim3(64, 4), 256, 0, stream>>>(partials, Lrow, out0, E);

  // sim = E @ E^T -> t = sigmoid(sim)*decay*mask + 1e-6, + fused row stats
  if (useAux)
    gemm_bf16_kernel<128, 128, 3><<<dim3(32, 32), 256, 0, stream>>>(
        E, E, 4096, 4096, 256, nullptr, nullptr,
        nullptr, nullptr, aux, t, Bsum, Bsq);
  else
    gemm_bf16_kernel<128, 128, 2><<<dim3(32, 32), 256, 0, stream>>>(
        E, E, 4096, 4096, 256, nullptr, nullptr,
        dist, degree, nullptr, t, Bsum, Bsq);

  stats_small_kernel<<<16, 256, 0, stream>>>(Bsum, Bsq, mean, rstd);

  finalize_kernel<<<dim3(64, 64), 256, 0, stream>>>(t, mean, rstd);
}

// Round 11
// 181.149 us; speedup vs baseline: 1.0361x; 1.0361x over previous
//
#include <hip/hip_runtime.h>

// GAT layer, N=4096, FIN=FOUT=256, H=1.
// prep (cvt nodes + Wt + zero Lrow) -> proj GEMM -> s_src/s_tgt -> score_exp
// (NT-load streaming map + in-wave rowsum atomics; P bf16, aux bf16) ->
// split-K GEMM P@projT (BN=128, bf16 partials) -> reduce (NT partials, /Lrow,
// elu -> out0 NT + E) -> sim GEMM (E E^T): epilogue reads aux[idx] (NT) and
// overwrites it IN PLACE with t=bf16(sigmoid*aux+1e-6), + fused row stats ->
// stats_small -> finalize: NT-read bf16 t from ws, write f32 upd=LN+LN^T (NT).

using f32x4  = __attribute__((ext_vector_type(4))) float;
using bf16x8 = __attribute__((ext_vector_type(8))) __bf16;
using bf16x4 = __attribute__((ext_vector_type(4))) __bf16;
using u32x4  = __attribute__((ext_vector_type(4))) unsigned int;

// grid 1280: bx<1024 -> bf16 cvt of nodes; bx>=1024 -> Wt transpose (+Lrow=0)
__global__ __launch_bounds__(256) void prep_kernel(const float* __restrict__ x,
                                                   __bf16* __restrict__ y,
                                                   const float* __restrict__ w,
                                                   __bf16* __restrict__ wt,
                                                   float* __restrict__ Lrow) {
  const int bx = blockIdx.x;
  if (bx < 1024) {
    int i = (bx * 256 + threadIdx.x) * 4;
    f32x4 v = *(const f32x4*)(x + i);
    bf16x4 o = { (__bf16)v[0], (__bf16)v[1], (__bf16)v[2], (__bf16)v[3] };
    *(bf16x4*)(y + i) = o;
  } else {
    int wb = bx - 1024;
    int i = wb * 256 + threadIdx.x;
    int o = i >> 8, f = i & 255;
    wt[i] = (__bf16)w[f * 256 + o];
    if (wb < 16) Lrow[wb * 256 + threadIdx.x] = 0.0f;
  }
}

// Generic bf16 GEMM: C[m,n] = sum_k A[m,k] * Bt[n,k].
// MODE 0: write proj f32 [m*256+n], projT bf16 [n*4096+m]
// MODE 2: t(f32, outt) = sigmoid(v)*(-e0)*(e1>0)+1e-6      (+ fused row stats)
// MODE 3: axt[idx] (bf16) <- bf16(sigmoid(v)*NT(axt[idx])+1e-6)  in-place
//         (+ fused row stats on the rounded value)
template<int BM, int BN, int MODE>
__global__ __launch_bounds__(256) void gemm_bf16_kernel(
    const __bf16* __restrict__ A, const __bf16* __restrict__ Bt,
    int M, int N, int K,
    float* __restrict__ outf, __bf16* __restrict__ outb,
    const float* __restrict__ e0, const float* __restrict__ e1,
    __bf16* __restrict__ axt, float* __restrict__ outt,
    float* __restrict__ bsum, float* __restrict__ bsq)
{
  constexpr int LDT = 72;
  constexpr int MI = BM / 32;
  constexpr int NI = BN / 32;
  __shared__ alignas(16) __bf16 As[BM * LDT];
  __shared__ alignas(16) __bf16 Bs[BN * LDT];
  const int tid  = threadIdx.x;
  const int lane = tid & 63;
  const int wid  = tid >> 6;
  const int wm0  = (wid >> 1) * (BM / 2);
  const int wn0  = (wid & 1) * (BN / 2);
  const int m0   = blockIdx.x * BM;
  const int n0   = blockIdx.y * BN;
  const int lr   = lane & 15;
  const int lk   = lane >> 4;

  f32x4 acc[MI][NI];
#pragma unroll
  for (int a = 0; a < MI; ++a)
#pragma unroll
    for (int b = 0; b < NI; ++b) acc[a][b] = (f32x4){0.f, 0.f, 0.f, 0.f};

  for (int kt = 0; kt < K; kt += 64) {
    __syncthreads();
    for (int idx = tid; idx < BM * 8; idx += 256) {
      int r = idx >> 3, c = idx & 7;
      u32x4 v = *(const u32x4*)(A + (size_t)(m0 + r) * K + kt + c * 8);
      *(u32x4*)(As + r * LDT + c * 8) = v;
    }
    for (int idx = tid; idx < BN * 8; idx += 256) {
      int r = idx >> 3, c = idx & 7;
      u32x4 v = *(const u32x4*)(Bt + (size_t)(n0 + r) * K + kt + c * 8);
      *(u32x4*)(Bs + r * LDT + c * 8) = v;
    }
    __syncthreads();
#pragma unroll
    for (int kk = 0; kk < 2; ++kk) {
      bf16x8 av[MI], bv[NI];
#pragma unroll
      for (int mi = 0; mi < MI; ++mi)
        av[mi] = *(const bf16x8*)(As + (wm0 + mi * 16 + lr) * LDT + kk * 32 + lk * 8);
#pragma unroll
      for (int ni = 0; ni < NI; ++ni)
        bv[ni] = *(const bf16x8*)(Bs + (wn0 + ni * 16 + lr) * LDT + kk * 32 + lk * 8);
#pragma unroll
      for (int mi = 0; mi < MI; ++mi)
#pragma unroll
        for (int ni = 0; ni < NI; ++ni)
          acc[mi][ni] = __builtin_amdgcn_mfma_f32_16x16x32_bf16(av[mi], bv[ni], acc[mi][ni], 0, 0, 0);
    }
  }

  if constexpr (MODE == 0) {
#pragma unroll
    for (int mi = 0; mi < MI; ++mi)
#pragma unroll
      for (int ni = 0; ni < NI; ++ni)
#pragma unroll
        for (int j = 0; j < 4; ++j) {
          const int m = m0 + wm0 + mi * 16 + lk * 4 + j;
          const int n = n0 + wn0 + ni * 16 + lr;
          const float v = acc[mi][ni][j];
          outf[(size_t)m * 256 + n] = v;
          outb[(size_t)n * 4096 + m] = (__bf16)v;
        }
  } else {
    // epilogue + fused per-row stats (sum over this block's BN columns)
#pragma unroll
    for (int mi = 0; mi < MI; ++mi) {
#pragma unroll
      for (int j = 0; j < 4; ++j) {
        const int m = m0 + wm0 + mi * 16 + lk * 4 + j;
        float s = 0.f, s2 = 0.f;
#pragma unroll
        for (int ni = 0; ni < NI; ++ni) {
          const int n = n0 + wn0 + ni * 16 + lr;
          const size_t idx = (size_t)m * 4096 + n;
          const float v = acc[mi][ni][j];
          const float sg = 1.0f / (1.0f + __expf(-v));
          float tr;
          if constexpr (MODE == 2) {
            const float d = e0[idx];
            const float g = e1[idx];
            const float tval = sg * (-d) * (g > 0.f ? 1.0f : 0.0f) + 1e-6f;
            outt[idx] = tval;
            tr = tval;
          } else {
            const float a = (float)__builtin_nontemporal_load(axt + idx);
            const __bf16 tb = (__bf16)(sg * a + 1e-6f);
            axt[idx] = tb;               // in-place: aux -> t (bf16)
            tr = (float)tb;              // stats on the rounded value
          }
          s += tr;
          s2 += tr * tr;
        }
#pragma unroll
        for (int o = 1; o < 16; o <<= 1) {
          s  += __shfl_xor(s, o, 64);
          s2 += __shfl_xor(s2, o, 64);
        }
        if (lr == 0) {
          const int slot = blockIdx.y * 2 + (wid & 1);   // 64 col-slots
          bsum[(size_t)slot * 4096 + m] = s;
          bsq [(size_t)slot * 4096 + m] = s2;
        }
      }
    }
  }
}

// mean/rstd from 64 column-block partial sums. grid 16 x 256.
__global__ __launch_bounds__(256) void stats_small_kernel(
    const float* __restrict__ bsum, const float* __restrict__ bsq,
    float* __restrict__ mean, float* __restrict__ rstd)
{
  const int row = blockIdx.x * 256 + threadIdx.x;
  float S = 0.f, S2 = 0.f;
#pragma unroll 8
  for (int s = 0; s < 64; ++s) {
    S  += bsum[(size_t)s * 4096 + row];
    S2 += bsq [(size_t)s * 4096 + row];
  }
  const float m  = S * (1.0f / 4096.0f);
  const float var = S2 * (1.0f / 4096.0f) - m * m;
  mean[row] = m;
  rstd[row] = rsqrtf(var + 1e-5f);
}

// NT-load streaming map + in-wave rowsum. dist/bond/deg single-use -> nt.
__global__ __launch_bounds__(256) void score_exp_kernel(
    const float* __restrict__ dist, const float* __restrict__ bond,
    const float* __restrict__ deg,  const float* __restrict__ ssrc,
    const float* __restrict__ stgt, const float* __restrict__ wdp,
    const float* __restrict__ wbp,  __bf16* __restrict__ P,
    __bf16* __restrict__ aux,       float* __restrict__ Lrow)
{
  const float wd = wdp[0], wb = wbp[0];
  const int lane = threadIdx.x & 63;
  size_t i = ((size_t)blockIdx.x * 256 + threadIdx.x) * 4;
  const size_t stride = (size_t)4096 * 256 * 4;
#pragma unroll 2
  for (int it = 0; it < 4; ++it, i += stride) {
    const int row = (int)(i >> 12);
    const int col = (int)(i & 4095);
    f32x4 d  = __builtin_nontemporal_load((const f32x4*)(dist + i));
    f32x4 g  = __builtin_nontemporal_load((const f32x4*)(deg + i));
    f32x4 b  = __builtin_nontemporal_load((const f32x4*)(bond + i));
    f32x4 st = *(const f32x4*)(stgt + col);
    const float si = ssrc[row];
    f32x4 p;
    bf16x4 pb, ab;
#pragma unroll
    for (int q = 0; q < 4; ++q) {
      float x = si + st[q];
      x = x > 0.f ? x : 0.2f * x;
      x += -d[q] * wd + b[q] * wb + (g[q] > 0.f ? g[q] : -1000000.0f);
      p[q] = __expf(x);
      pb[q] = (__bf16)p[q];
      ab[q] = (__bf16)(g[q] > 0.f ? -d[q] : 0.0f);
    }
    *(bf16x4*)(P + i) = pb;
    if (aux) *(bf16x4*)(aux + i) = ab;
    float s = p[0] + p[1] + p[2] + p[3];
#pragma unroll
    for (int o = 32; o; o >>= 1) s += __shfl_xor(s, o, 64);
    if (lane == 0) atomicAdd(Lrow + row, s);   // whole wave is in one row
  }
}

// split-K GEMM: partial[s][m*256+n] (bf16), BM=64 BN=128, K-chunk 512.
__global__ __launch_bounds__(256) void gemm_splitk_kernel(
    const __bf16* __restrict__ A, const __bf16* __restrict__ Bt,
    __bf16* __restrict__ partial)
{
  constexpr int LDT = 72;
  __shared__ alignas(16) __bf16 As[64 * LDT];
  __shared__ alignas(16) __bf16 Bs[128 * LDT];
  const int tid  = threadIdx.x;
  const int lane = tid & 63;
  const int wid  = tid >> 6;
  const int wm0  = (wid >> 1) * 32;
  const int wn0  = (wid & 1) * 64;
  const int m0   = blockIdx.x * 64;
  const int n0   = blockIdx.y * 128;
  const int s    = blockIdx.z;
  const int lr   = lane & 15;
  const int lk   = lane >> 4;

  f32x4 acc[2][4];
#pragma unroll
  for (int a = 0; a < 2; ++a)
#pragma unroll
    for (int b = 0; b < 4; ++b) acc[a][b] = (f32x4){0.f, 0.f, 0.f, 0.f};

  const int k0 = s * 512;
  for (int kt = k0; kt < k0 + 512; kt += 64) {
    __syncthreads();
    for (int idx = tid; idx < 512; idx += 256) {
      int r = idx >> 3, c = idx & 7;
      u32x4 v = *(const u32x4*)(A + (size_t)(m0 + r) * 4096 + kt + c * 8);
      *(u32x4*)(As + r * LDT + c * 8) = v;
    }
    for (int idx = tid; idx < 1024; idx += 256) {
      int r = idx >> 3, c = idx & 7;
      u32x4 v = *(const u32x4*)(Bt + (size_t)(n0 + r) * 4096 + kt + c * 8);
      *(u32x4*)(Bs + r * LDT + c * 8) = v;
    }
    __syncthreads();
#pragma unroll
    for (int kk = 0; kk < 2; ++kk) {
      bf16x8 av[2], bv[4];
#pragma unroll
      for (int mi = 0; mi < 2; ++mi)
        av[mi] = *(const bf16x8*)(As + (wm0 + mi * 16 + lr) * LDT + kk * 32 + lk * 8);
#pragma unroll
      for (int ni = 0; ni < 4; ++ni)
        bv[ni] = *(const bf16x8*)(Bs + (wn0 + ni * 16 + lr) * LDT + kk * 32 + lk * 8);
#pragma unroll
      for (int mi = 0; mi < 2; ++mi)
#pragma unroll
        for (int ni = 0; ni < 4; ++ni)
          acc[mi][ni] = __builtin_amdgcn_mfma_f32_16x16x32_bf16(av[mi], bv[ni], acc[mi][ni], 0, 0, 0);
    }
  }

  __bf16* Pp = partial + (size_t)s * (4096 * 256);
#pragma unroll
  for (int mi = 0; mi < 2; ++mi)
#pragma unroll
    for (int ni = 0; ni < 4; ++ni)
#pragma unroll
      for (int j = 0; j < 4; ++j) {
        const int m = m0 + wm0 + mi * 16 + lk * 4 + j;
        const int n = n0 + wn0 + ni * 16 + lr;
        Pp[(size_t)m * 256 + n] = (__bf16)acc[mi][ni][j];
      }
}

// sum 8 bf16 partials (NT), /Lrow, elu -> out0 (NT store) + E (bf16).
__global__ __launch_bounds__(256) void reduce_elu_kernel(
    const __bf16* __restrict__ partial, const float* __restrict__ Lrow,
    float* __restrict__ out0, __bf16* __restrict__ E)
{
  __shared__ float tile[64][65];
  __shared__ float invL[64];
  const int tid = threadIdx.x;
  const int m0 = blockIdx.x * 64;
  const int f0 = blockIdx.y * 64;
  if (tid < 64) invL[tid] = 1.0f / Lrow[m0 + tid];
  f32x4 accv[4];
#pragma unroll
  for (int i = 0; i < 4; ++i) {
    int lin = i * 1024 + tid * 4;
    int r = lin >> 6, c = lin & 63;
    f32x4 sum = (f32x4){0.f, 0.f, 0.f, 0.f};
#pragma unroll
    for (int s = 0; s < 8; ++s) {
      bf16x4 pv = __builtin_nontemporal_load(
          (const bf16x4*)(partial + (size_t)s * (4096 * 256) +
                          (size_t)(m0 + r) * 256 + f0 + c));
#pragma unroll
      for (int q = 0; q < 4; ++q) sum[q] += (float)pv[q];
    }
    accv[i] = sum;
  }
  __syncthreads();   // invL ready
#pragma unroll
  for (int i = 0; i < 4; ++i) {
    int lin = i * 1024 + tid * 4;
    int r = lin >> 6, c = lin & 63;
    const float inv = invL[r];
    tile[r][c]     = accv[i][0] * inv;
    tile[r][c + 1] = accv[i][1] * inv;
    tile[r][c + 2] = accv[i][2] * inv;
    tile[r][c + 3] = accv[i][3] * inv;
  }
  __syncthreads();
#pragma unroll
  for (int i = 0; i < 4; ++i) {
    int lin = i * 1024 + tid * 4;
    int rr = lin >> 6, cc = lin & 63;   // rr: feature offset, cc: node offset
    f32x4 e;
#pragma unroll
    for (int q = 0; q < 4; ++q) {
      float v = tile[cc + q][rr];
      e[q] = v > 0.f ? v : expm1f(v);
    }
    size_t idx = (size_t)(f0 + rr) * 4096 + m0 + cc;
    __builtin_nontemporal_store(e, (f32x4*)(out0 + idx));
    bf16x4 eb = { (__bf16)e[0], (__bf16)e[1], (__bf16)e[2], (__bf16)e[3] };
    *(bf16x4*)(E + idx) = eb;
  }
}

// s_src[n] = proj[n,:].a_src ; s_tgt[n] = proj[n,:].a_tgt
__global__ __launch_bounds__(256) void sproj_kernel(const float* __restrict__ proj,
                                                    const float* __restrict__ asrc,
                                                    const float* __restrict__ atgt,
                                                    float* __restrict__ ssrc,
                                                    float* __restrict__ stgt) {
  const int row  = blockIdx.x * 4 + (threadIdx.x >> 6);
  const int lane = threadIdx.x & 63;
  f32x4 p = *(const f32x4*)(proj + (size_t)row * 256 + lane * 4);
  f32x4 a = *(const f32x4*)(asrc + lane * 4);
  f32x4 b = *(const f32x4*)(atgt + lane * 4);
  float d1 = p[0]*a[0] + p[1]*a[1] + p[2]*a[2] + p[3]*a[3];
  float d2 = p[0]*b[0] + p[1]*b[1] + p[2]*b[2] + p[3]*b[3];
#pragma unroll
  for (int o = 32; o; o >>= 1) { d1 += __shfl_xor(d1, o, 64); d2 += __shfl_xor(d2, o, 64); }
  if (lane == 0) { ssrc[row] = d1; stgt[row] = d2; }
}

// upd[i,j] = (t[i,j]-mean_i)*rstd_i + (t[j,i]-mean_j)*rstd_j
// t is bf16 in ws (NT reads, single-use); upd f32 written NT (never re-read).
__global__ __launch_bounds__(256) void finalize_bf16_kernel(
    const __bf16* __restrict__ tb, float* __restrict__ upd,
    const float* __restrict__ mean, const float* __restrict__ rstd)
{
  const int bj = blockIdx.x, bi = blockIdx.y;
  if (bi > bj) return;
  __shared__ float ta[64][65];
  __shared__ float tc[64][65];
  const int tid = threadIdx.x;
#pragma unroll
  for (int i = 0; i < 4; ++i) {
    int lin = i * 1024 + tid * 4;
    int r = lin >> 6, c = lin & 63;
    bf16x4 va = __builtin_nontemporal_load(
        (const bf16x4*)(tb + (size_t)(bi * 64 + r) * 4096 + bj * 64 + c));
    ta[r][c] = (float)va[0]; ta[r][c+1] = (float)va[1];
    ta[r][c+2] = (float)va[2]; ta[r][c+3] = (float)va[3];
  }
  if (bi != bj) {
#pragma unroll
    for (int i = 0; i < 4; ++i) {
      int lin = i * 1024 + tid * 4;
      int r = lin >> 6, c = lin & 63;
      bf16x4 vb = __builtin_nontemporal_load(
          (const bf16x4*)(tb + (size_t)(bj * 64 + r) * 4096 + bi * 64 + c));
      tc[r][c] = (float)vb[0]; tc[r][c+1] = (float)vb[1];
      tc[r][c+2] = (float)vb[2]; tc[r][c+3] = (float)vb[3];
    }
  }
  __syncthreads();
#pragma unroll
  for (int i = 0; i < 4; ++i) {
    int lin = i * 1024 + tid * 4;
    int r = lin >> 6, c = lin & 63;
    int gi = bi * 64 + r, gj = bj * 64 + c;
    const float mi_ = mean[gi], ri_ = rstd[gi];
    f32x4 mj = *(const f32x4*)(mean + gj);
    f32x4 rj = *(const f32x4*)(rstd + gj);
    f32x4 o;
#pragma unroll
    for (int q = 0; q < 4; ++q) {
      float v = (ta[r][c + q] - mi_) * ri_;
      float w = (bi == bj) ? (ta[c + q][r] - mj[q]) * rj[q]
                           : (tc[c + q][r] - mj[q]) * rj[q];
      o[q] = v + w;
    }
    __builtin_nontemporal_store(o, (f32x4*)(upd + (size_t)gi * 4096 + gj));
  }
  if (bi != bj) {
#pragma unroll
    for (int i = 0; i < 4; ++i) {
      int lin = i * 1024 + tid * 4;
      int r = lin >> 6, c = lin & 63;
      int gi = bj * 64 + r, gj = bi * 64 + c;
      const float mi_ = mean[gi], ri_ = rstd[gi];
      f32x4 mj = *(const f32x4*)(mean + gj);
      f32x4 rj = *(const f32x4*)(rstd + gj);
      f32x4 o;
#pragma unroll
      for (int q = 0; q < 4; ++q) {
        float v = (tc[r][c + q] - mi_) * ri_;
        float w = (ta[c + q][r] - mj[q]) * rj[q];
        o[q] = v + w;
      }
      __builtin_nontemporal_store(o, (f32x4*)(upd + (size_t)gi * 4096 + gj));
    }
  }
}

// fallback (no-aux path): in-place f32 t -> upd, as before.
__global__ __launch_bounds__(256) void finalize_f32_kernel(
    float* __restrict__ t, const float* __restrict__ mean,
    const float* __restrict__ rstd)
{
  const int bj = blockIdx.x, bi = blockIdx.y;
  if (bi > bj) return;
  __shared__ float ta[64][65];
  __shared__ float tc[64][65];
  const int tid = threadIdx.x;
#pragma unroll
  for (int i = 0; i < 4; ++i) {
    int lin = i * 1024 + tid * 4;
    int r = lin >> 6, c = lin & 63;
    f32x4 va = *(const f32x4*)(t + (size_t)(bi * 64 + r) * 4096 + bj * 64 + c);
    ta[r][c] = va[0]; ta[r][c+1] = va[1]; ta[r][c+2] = va[2]; ta[r][c+3] = va[3];
  }
  if (bi != bj) {
#pragma unroll
    for (int i = 0; i < 4; ++i) {
      int lin = i * 1024 + tid * 4;
      int r = lin >> 6, c = lin & 63;
      f32x4 vb = *(const f32x4*)(t + (size_t)(bj * 64 + r) * 4096 + bi * 64 + c);
      tc[r][c] = vb[0]; tc[r][c+1] = vb[1]; tc[r][c+2] = vb[2]; tc[r][c+3] = vb[3];
    }
  }
  __syncthreads();
#pragma unroll
  for (int i = 0; i < 4; ++i) {
    int lin = i * 1024 + tid * 4;
    int r = lin >> 6, c = lin & 63;
    int gi = bi * 64 + r, gj = bj * 64 + c;
    const float mi_ = mean[gi], ri_ = rstd[gi];
    f32x4 mj = *(const f32x4*)(mean + gj);
    f32x4 rj = *(const f32x4*)(rstd + gj);
    f32x4 o;
#pragma unroll
    for (int q = 0; q < 4; ++q) {
      float v = (ta[r][c + q] - mi_) * ri_;
      float w = (bi == bj) ? (ta[c + q][r] - mj[q]) * rj[q]
                           : (tc[c + q][r] - mj[q]) * rj[q];
      o[q] = v + w;
    }
    *(f32x4*)(t + (size_t)gi * 4096 + gj) = o;
  }
  if (bi != bj) {
#pragma unroll
    for (int i = 0; i < 4; ++i) {
      int lin = i * 1024 + tid * 4;
      int r = lin >> 6, c = lin & 63;
      int gi = bj * 64 + r, gj = bi * 64 + c;
      const float mi_ = mean[gi], ri_ = rstd[gi];
      f32x4 mj = *(const f32x4*)(mean + gj);
      f32x4 rj = *(const f32x4*)(rstd + gj);
      f32x4 o;
#pragma unroll
      for (int q = 0; q < 4; ++q) {
        float v = (tc[r][c + q] - mi_) * ri_;
        float w = (ta[c + q][r] - mj[q]) * rj[q];
        o[q] = v + w;
      }
      *(f32x4*)(t + (size_t)gi * 4096 + gj) = o;
    }
  }
}

extern "C" void kernel_launch(void* const* d_in, const int* in_sizes, int n_in,
                              void* d_out, int out_size, void* d_ws, size_t ws_size,
                              hipStream_t stream) {
  const float* nodes  = (const float*)d_in[0];
  const float* degree = (const float*)d_in[1];
  const float* dist   = (const float*)d_in[2];
  const float* bond   = (const float*)d_in[3];
  const float* W      = (const float*)d_in[4];
  const float* a_src  = (const float*)d_in[5];
  const float* a_tgt  = (const float*)d_in[6];
  const float* w_dist = (const float*)d_in[7];
  const float* w_bond = (const float*)d_in[8];

  char* ws = (char*)d_ws;
  __bf16* nodesB = (__bf16*)ws;                                  // 2 MB
  __bf16* Wt     = (__bf16*)(ws + (2u << 20));                   // 128 KB
  __bf16* projT  = (__bf16*)(ws + (2u << 20) + (256u << 10));    // 2 MB
  float*  proj   = (float*)(ws + (5u << 20));                    // 4 MB
  __bf16* E      = (__bf16*)(ws + (9u << 20));                   // 2 MB
  float*  ssrc   = (float*)(ws + (11u << 20));                   // 16 KB
  float*  stgt   = ssrc + 4096;
  float*  mean   = stgt + 4096;
  float*  rstd   = mean + 4096;
  float*  Lrow   = rstd + 4096;                                  // 16 KB

  // aux (32 MB at +12 MB; becomes bf16 t in place) + Bsum/Bsq at +44 MB.
  const bool useAux = ws_size >= (size_t)(48u << 20);
  __bf16* aux  = useAux ? (__bf16*)(ws + (12u << 20)) : nullptr;
  float* Bsum  = useAux ? (float*)(ws + (44u << 20))
                        : (float*)(ws + (12u << 20));
  float* Bsq   = Bsum + (size_t)64 * 4096;

  float*  out0 = (float*)d_out;                 // 4096*256 f32 (output 0)
  float*  t    = out0 + (size_t)4096 * 256;     // 4096*4096 f32 (output 1 region)
  __bf16* P    = (__bf16*)t;                    // exp-scores bf16: lower 32 MiB
  __bf16* partials = (__bf16*)((char*)t + ((size_t)32 << 20)); // 8 x 2 MB bf16

  prep_kernel<<<1280, 256, 0, stream>>>(nodes, nodesB, W, Wt, Lrow);

  // proj = nodes @ W   (M=4096, N=256, K=256)
  gemm_bf16_kernel<64, 64, 0><<<dim3(64, 4), 256, 0, stream>>>(
      nodesB, Wt, 4096, 256, 256, proj, projT,
      nullptr, nullptr, nullptr, nullptr, nullptr, nullptr);

  sproj_kernel<<<1024, 256, 0, stream>>>(proj, a_src, a_tgt, ssrc, stgt);

  // P = exp(scores), aux, Lrow — NT-load streaming map
  score_exp_kernel<<<4096, 256, 0, stream>>>(dist, bond, degree, ssrc, stgt,
                                             w_dist, w_bond, P, aux, Lrow);

  // agg-partials (bf16) = P @ projT, split-K over 8 chunks of 512
  gemm_splitk_kernel<<<dim3(64, 2, 8), 256, 0, stream>>>(P, projT, partials);

  // sum partials, /Lrow, elu -> out0 (f32, transposed, NT) + E (bf16)
  reduce_elu_kernel<<<dim3(64, 4), 256, 0, stream>>>(partials, Lrow, out0, E);

  // sim = E @ E^T -> t, + fused row stats
  if (useAux) {
    // t = bf16(sigmoid(sim)*aux + 1e-6) written IN PLACE over aux
    gemm_bf16_kernel<128, 128, 3><<<dim3(32, 32), 256, 0, stream>>>(
        E, E, 4096, 4096, 256, nullptr, nullptr,
        nullptr, nullptr, aux, nullptr, Bsum, Bsq);
    stats_small_kernel<<<16, 256, 0, stream>>>(Bsum, Bsq, mean, rstd);
    finalize_bf16_kernel<<<dim3(64, 64), 256, 0, stream>>>(aux, t, mean, rstd);
  } else {
    gemm_bf16_kernel<128, 128, 2><<<dim3(32, 32), 256, 0, stream>>>(
        E, E, 4096, 4096, 256, nullptr, nullptr,
        dist, degree, nullptr, t, Bsum, Bsq);
    stats_small_kernel<<<16, 256, 0, stream>>>(Bsum, Bsq, mean, rstd);
    finalize_f32_kernel<<<dim3(64, 64), 256, 0, stream>>>(t, mean, rstd);
  }
}

// Round 12
// 179.512 us; speedup vs baseline: 1.0455x; 1.0091x over previous
//
#include <hip/hip_runtime.h>

// GAT layer, N=4096, FIN=FOUT=256, H=1.
// prep (cvt nodes + Wt + zero Lrow/ssrc/stgt) -> proj GEMM (projT bf16 + FUSED
// s_src/s_tgt via shuffle-reduce + atomicAdd) -> score_exp (single-pass NT-load
// streaming map + in-wave rowsum atomics; P bf16, aux bf16) -> split-K GEMM
// P@projT (BN=128, bf16 partials) -> reduce (NT partials, /Lrow, elu -> out0 NT
// + E) -> sim GEMM (E E^T): epilogue reads aux[idx] (NT) and overwrites it IN
// PLACE with t=bf16(sigmoid*aux+1e-6), + fused row stats -> stats_small ->
// finalize: NT-read bf16 t from ws, write f32 upd=LN+LN^T (NT).

using f32x4  = __attribute__((ext_vector_type(4))) float;
using bf16x8 = __attribute__((ext_vector_type(8))) __bf16;
using bf16x4 = __attribute__((ext_vector_type(4))) __bf16;
using u32x4  = __attribute__((ext_vector_type(4))) unsigned int;

// grid 1280: bx<1024 -> bf16 cvt of nodes; bx>=1024 -> Wt transpose
// (+ zero Lrow / ssrc / stgt)
__global__ __launch_bounds__(256) void prep_kernel(const float* __restrict__ x,
                                                   __bf16* __restrict__ y,
                                                   const float* __restrict__ w,
                                                   __bf16* __restrict__ wt,
                                                   float* __restrict__ Lrow,
                                                   float* __restrict__ ssrc,
                                                   float* __restrict__ stgt) {
  const int bx = blockIdx.x;
  if (bx < 1024) {
    int i = (bx * 256 + threadIdx.x) * 4;
    f32x4 v = *(const f32x4*)(x + i);
    bf16x4 o = { (__bf16)v[0], (__bf16)v[1], (__bf16)v[2], (__bf16)v[3] };
    *(bf16x4*)(y + i) = o;
  } else {
    int wb = bx - 1024;
    int i = wb * 256 + threadIdx.x;
    int o = i >> 8, f = i & 255;
    wt[i] = (__bf16)w[f * 256 + o];
    if (wb < 16)              Lrow[wb * 256 + threadIdx.x] = 0.0f;
    else if (wb < 32)         ssrc[(wb - 16) * 256 + threadIdx.x] = 0.0f;
    else if (wb < 48)         stgt[(wb - 32) * 256 + threadIdx.x] = 0.0f;
  }
}

// Generic bf16 GEMM: C[m,n] = sum_k A[m,k] * Bt[n,k].
// MODE 0: projT bf16 [n*4096+m]; FUSED s_src/s_tgt: e0=a_src, e1=a_tgt,
//         bsum=ssrc, bsq=stgt (atomicAdd of per-block row dots)
// MODE 2: t(f32, outt) = sigmoid(v)*(-e0)*(e1>0)+1e-6      (+ fused row stats)
// MODE 3: axt[idx] (bf16) <- bf16(sigmoid(v)*NT(axt[idx])+1e-6)  in-place
//         (+ fused row stats on the rounded value)
template<int BM, int BN, int MODE>
__global__ __launch_bounds__(256) void gemm_bf16_kernel(
    const __bf16* __restrict__ A, const __bf16* __restrict__ Bt,
    int M, int N, int K,
    float* __restrict__ outf, __bf16* __restrict__ outb,
    const float* __restrict__ e0, const float* __restrict__ e1,
    __bf16* __restrict__ axt, float* __restrict__ outt,
    float* __restrict__ bsum, float* __restrict__ bsq)
{
  constexpr int LDT = 72;
  constexpr int MI = BM / 32;
  constexpr int NI = BN / 32;
  __shared__ alignas(16) __bf16 As[BM * LDT];
  __shared__ alignas(16) __bf16 Bs[BN * LDT];
  const int tid  = threadIdx.x;
  const int lane = tid & 63;
  const int wid  = tid >> 6;
  const int wm0  = (wid >> 1) * (BM / 2);
  const int wn0  = (wid & 1) * (BN / 2);
  const int m0   = blockIdx.x * BM;
  const int n0   = blockIdx.y * BN;
  const int lr   = lane & 15;
  const int lk   = lane >> 4;

  f32x4 acc[MI][NI];
#pragma unroll
  for (int a = 0; a < MI; ++a)
#pragma unroll
    for (int b = 0; b < NI; ++b) acc[a][b] = (f32x4){0.f, 0.f, 0.f, 0.f};

  for (int kt = 0; kt < K; kt += 64) {
    __syncthreads();
    for (int idx = tid; idx < BM * 8; idx += 256) {
      int r = idx >> 3, c = idx & 7;
      u32x4 v = *(const u32x4*)(A + (size_t)(m0 + r) * K + kt + c * 8);
      *(u32x4*)(As + r * LDT + c * 8) = v;
    }
    for (int idx = tid; idx < BN * 8; idx += 256) {
      int r = idx >> 3, c = idx & 7;
      u32x4 v = *(const u32x4*)(Bt + (size_t)(n0 + r) * K + kt + c * 8);
      *(u32x4*)(Bs + r * LDT + c * 8) = v;
    }
    __syncthreads();
#pragma unroll
    for (int kk = 0; kk < 2; ++kk) {
      bf16x8 av[MI], bv[NI];
#pragma unroll
      for (int mi = 0; mi < MI; ++mi)
        av[mi] = *(const bf16x8*)(As + (wm0 + mi * 16 + lr) * LDT + kk * 32 + lk * 8);
#pragma unroll
      for (int ni = 0; ni < NI; ++ni)
        bv[ni] = *(const bf16x8*)(Bs + (wn0 + ni * 16 + lr) * LDT + kk * 32 + lk * 8);
#pragma unroll
      for (int mi = 0; mi < MI; ++mi)
#pragma unroll
        for (int ni = 0; ni < NI; ++ni)
          acc[mi][ni] = __builtin_amdgcn_mfma_f32_16x16x32_bf16(av[mi], bv[ni], acc[mi][ni], 0, 0, 0);
    }
  }

  if constexpr (MODE == 0) {
    // projT + fused s_src/s_tgt row dots
#pragma unroll
    for (int mi = 0; mi < MI; ++mi) {
#pragma unroll
      for (int j = 0; j < 4; ++j) {
        const int m = m0 + wm0 + mi * 16 + lk * 4 + j;
        float s1 = 0.f, s2 = 0.f;
#pragma unroll
        for (int ni = 0; ni < NI; ++ni) {
          const int n = n0 + wn0 + ni * 16 + lr;
          const float v = acc[mi][ni][j];
          outb[(size_t)n * 4096 + m] = (__bf16)v;
          s1 += v * e0[n];
          s2 += v * e1[n];
        }
#pragma unroll
        for (int o = 1; o < 16; o <<= 1) {
          s1 += __shfl_xor(s1, o, 64);
          s2 += __shfl_xor(s2, o, 64);
        }
        if (lr == 0) {
          atomicAdd(bsum + m, s1);
          atomicAdd(bsq + m, s2);
        }
      }
    }
  } else {
    // epilogue + fused per-row stats (sum over this block's BN columns)
#pragma unroll
    for (int mi = 0; mi < MI; ++mi) {
#pragma unroll
      for (int j = 0; j < 4; ++j) {
        const int m = m0 + wm0 + mi * 16 + lk * 4 + j;
        float s = 0.f, s2 = 0.f;
#pragma unroll
        for (int ni = 0; ni < NI; ++ni) {
          const int n = n0 + wn0 + ni * 16 + lr;
          const size_t idx = (size_t)m * 4096 + n;
          const float v = acc[mi][ni][j];
          const float sg = 1.0f / (1.0f + __expf(-v));
          float tr;
          if constexpr (MODE == 2) {
            const float d = e0[idx];
            const float g = e1[idx];
            const float tval = sg * (-d) * (g > 0.f ? 1.0f : 0.0f) + 1e-6f;
            outt[idx] = tval;
            tr = tval;
          } else {
            const float a = (float)__builtin_nontemporal_load(axt + idx);
            const __bf16 tb = (__bf16)(sg * a + 1e-6f);
            axt[idx] = tb;               // in-place: aux -> t (bf16)
            tr = (float)tb;              // stats on the rounded value
          }
          s += tr;
          s2 += tr * tr;
        }
#pragma unroll
        for (int o = 1; o < 16; o <<= 1) {
          s  += __shfl_xor(s, o, 64);
          s2 += __shfl_xor(s2, o, 64);
        }
        if (lr == 0) {
          const int slot = blockIdx.y * 2 + (wid & 1);   // 64 col-slots
          bsum[(size_t)slot * 4096 + m] = s;
          bsq [(size_t)slot * 4096 + m] = s2;
        }
      }
    }
  }
}

// mean/rstd from 64 column-block partial sums. grid 16 x 256.
__global__ __launch_bounds__(256) void stats_small_kernel(
    const float* __restrict__ bsum, const float* __restrict__ bsq,
    float* __restrict__ mean, float* __restrict__ rstd)
{
  const int row = blockIdx.x * 256 + threadIdx.x;
  float S = 0.f, S2 = 0.f;
#pragma unroll 8
  for (int s = 0; s < 64; ++s) {
    S  += bsum[(size_t)s * 4096 + row];
    S2 += bsq [(size_t)s * 4096 + row];
  }
  const float m  = S * (1.0f / 4096.0f);
  const float var = S2 * (1.0f / 4096.0f) - m * m;
  mean[row] = m;
  rstd[row] = rsqrtf(var + 1e-5f);
}

// Single-pass NT-load streaming map + in-wave rowsum atomics.
// grid 16384 x 256: one f32x4 per stream per thread, no loop.
__global__ __launch_bounds__(256) void score_exp_kernel(
    const float* __restrict__ dist, const float* __restrict__ bond,
    const float* __restrict__ deg,  const float* __restrict__ ssrc,
    const float* __restrict__ stgt, const float* __restrict__ wdp,
    const float* __restrict__ wbp,  __bf16* __restrict__ P,
    __bf16* __restrict__ aux,       float* __restrict__ Lrow)
{
  const float wd = wdp[0], wb = wbp[0];
  const int lane = threadIdx.x & 63;
  const size_t i = ((size_t)blockIdx.x * 256 + threadIdx.x) * 4;
  const int row = (int)(i >> 12);
  const int col = (int)(i & 4095);
  f32x4 d  = __builtin_nontemporal_load((const f32x4*)(dist + i));
  f32x4 g  = __builtin_nontemporal_load((const f32x4*)(deg + i));
  f32x4 b  = __builtin_nontemporal_load((const f32x4*)(bond + i));
  f32x4 st = *(const f32x4*)(stgt + col);
  const float si = ssrc[row];
  f32x4 p;
  bf16x4 pb, ab;
#pragma unroll
  for (int q = 0; q < 4; ++q) {
    float x = si + st[q];
    x = x > 0.f ? x : 0.2f * x;
    x += -d[q] * wd + b[q] * wb + (g[q] > 0.f ? g[q] : -1000000.0f);
    p[q] = __expf(x);
    pb[q] = (__bf16)p[q];
    ab[q] = (__bf16)(g[q] > 0.f ? -d[q] : 0.0f);
  }
  *(bf16x4*)(P + i) = pb;
  if (aux) *(bf16x4*)(aux + i) = ab;
  float s = p[0] + p[1] + p[2] + p[3];
#pragma unroll
  for (int o = 32; o; o >>= 1) s += __shfl_xor(s, o, 64);
  if (lane == 0) atomicAdd(Lrow + row, s);   // whole wave is in one row
}

// split-K GEMM: partial[s][m*256+n] (bf16), BM=64 BN=128, K-chunk 512.
__global__ __launch_bounds__(256) void gemm_splitk_kernel(
    const __bf16* __restrict__ A, const __bf16* __restrict__ Bt,
    __bf16* __restrict__ partial)
{
  constexpr int LDT = 72;
  __shared__ alignas(16) __bf16 As[64 * LDT];
  __shared__ alignas(16) __bf16 Bs[128 * LDT];
  const int tid  = threadIdx.x;
  const int lane = tid & 63;
  const int wid  = tid >> 6;
  const int wm0  = (wid >> 1) * 32;
  const int wn0  = (wid & 1) * 64;
  const int m0   = blockIdx.x * 64;
  const int n0   = blockIdx.y * 128;
  const int s    = blockIdx.z;
  const int lr   = lane & 15;
  const int lk   = lane >> 4;

  f32x4 acc[2][4];
#pragma unroll
  for (int a = 0; a < 2; ++a)
#pragma unroll
    for (int b = 0; b < 4; ++b) acc[a][b] = (f32x4){0.f, 0.f, 0.f, 0.f};

  const int k0 = s * 512;
  for (int kt = k0; kt < k0 + 512; kt += 64) {
    __syncthreads();
    for (int idx = tid; idx < 512; idx += 256) {
      int r = idx >> 3, c = idx & 7;
      u32x4 v = *(const u32x4*)(A + (size_t)(m0 + r) * 4096 + kt + c * 8);
      *(u32x4*)(As + r * LDT + c * 8) = v;
    }
    for (int idx = tid; idx < 1024; idx += 256) {
      int r = idx >> 3, c = idx & 7;
      u32x4 v = *(const u32x4*)(Bt + (size_t)(n0 + r) * 4096 + kt + c * 8);
      *(u32x4*)(Bs + r * LDT + c * 8) = v;
    }
    __syncthreads();
#pragma unroll
    for (int kk = 0; kk < 2; ++kk) {
      bf16x8 av[2], bv[4];
#pragma unroll
      for (int mi = 0; mi < 2; ++mi)
        av[mi] = *(const bf16x8*)(As + (wm0 + mi * 16 + lr) * LDT + kk * 32 + lk * 8);
#pragma unroll
      for (int ni = 0; ni < 4; ++ni)
        bv[ni] = *(const bf16x8*)(Bs + (wn0 + ni * 16 + lr) * LDT + kk * 32 + lk * 8);
#pragma unroll
      for (int mi = 0; mi < 2; ++mi)
#pragma unroll
        for (int ni = 0; ni < 4; ++ni)
          acc[mi][ni] = __builtin_amdgcn_mfma_f32_16x16x32_bf16(av[mi], bv[ni], acc[mi][ni], 0, 0, 0);
    }
  }

  __bf16* Pp = partial + (size_t)s * (4096 * 256);
#pragma unroll
  for (int mi = 0; mi < 2; ++mi)
#pragma unroll
    for (int ni = 0; ni < 4; ++ni)
#pragma unroll
      for (int j = 0; j < 4; ++j) {
        const int m = m0 + wm0 + mi * 16 + lk * 4 + j;
        const int n = n0 + wn0 + ni * 16 + lr;
        Pp[(size_t)m * 256 + n] = (__bf16)acc[mi][ni][j];
      }
}

// sum 8 bf16 partials (NT), /Lrow, elu -> out0 (NT store) + E (bf16).
__global__ __launch_bounds__(256) void reduce_elu_kernel(
    const __bf16* __restrict__ partial, const float* __restrict__ Lrow,
    float* __restrict__ out0, __bf16* __restrict__ E)
{
  __shared__ float tile[64][65];
  __shared__ float invL[64];
  const int tid = threadIdx.x;
  const int m0 = blockIdx.x * 64;
  const int f0 = blockIdx.y * 64;
  if (tid < 64) invL[tid] = 1.0f / Lrow[m0 + tid];
  f32x4 accv[4];
#pragma unroll
  for (int i = 0; i < 4; ++i) {
    int lin = i * 1024 + tid * 4;
    int r = lin >> 6, c = lin & 63;
    f32x4 sum = (f32x4){0.f, 0.f, 0.f, 0.f};
#pragma unroll
    for (int s = 0; s < 8; ++s) {
      bf16x4 pv = __builtin_nontemporal_load(
          (const bf16x4*)(partial + (size_t)s * (4096 * 256) +
                          (size_t)(m0 + r) * 256 + f0 + c));
#pragma unroll
      for (int q = 0; q < 4; ++q) sum[q] += (float)pv[q];
    }
    accv[i] = sum;
  }
  __syncthreads();   // invL ready
#pragma unroll
  for (int i = 0; i < 4; ++i) {
    int lin = i * 1024 + tid * 4;
    int r = lin >> 6, c = lin & 63;
    const float inv = invL[r];
    tile[r][c]     = accv[i][0] * inv;
    tile[r][c + 1] = accv[i][1] * inv;
    tile[r][c + 2] = accv[i][2] * inv;
    tile[r][c + 3] = accv[i][3] * inv;
  }
  __syncthreads();
#pragma unroll
  for (int i = 0; i < 4; ++i) {
    int lin = i * 1024 + tid * 4;
    int rr = lin >> 6, cc = lin & 63;   // rr: feature offset, cc: node offset
    f32x4 e;
#pragma unroll
    for (int q = 0; q < 4; ++q) {
      float v = tile[cc + q][rr];
      e[q] = v > 0.f ? v : expm1f(v);
    }
    size_t idx = (size_t)(f0 + rr) * 4096 + m0 + cc;
    __builtin_nontemporal_store(e, (f32x4*)(out0 + idx));
    bf16x4 eb = { (__bf16)e[0], (__bf16)e[1], (__bf16)e[2], (__bf16)e[3] };
    *(bf16x4*)(E + idx) = eb;
  }
}

// upd[i,j] = (t[i,j]-mean_i)*rstd_i + (t[j,i]-mean_j)*rstd_j
// t is bf16 in ws (NT reads, single-use); upd f32 written NT (never re-read).
__global__ __launch_bounds__(256) void finalize_bf16_kernel(
    const __bf16* __restrict__ tb, float* __restrict__ upd,
    const float* __restrict__ mean, const float* __restrict__ rstd)
{
  const int bj = blockIdx.x, bi = blockIdx.y;
  if (bi > bj) return;
  __shared__ float ta[64][65];
  __shared__ float tc[64][65];
  const int tid = threadIdx.x;
#pragma unroll
  for (int i = 0; i < 4; ++i) {
    int lin = i * 1024 + tid * 4;
    int r = lin >> 6, c = lin & 63;
    bf16x4 va = __builtin_nontemporal_load(
        (const bf16x4*)(tb + (size_t)(bi * 64 + r) * 4096 + bj * 64 + c));
    ta[r][c] = (float)va[0]; ta[r][c+1] = (float)va[1];
    ta[r][c+2] = (float)va[2]; ta[r][c+3] = (float)va[3];
  }
  if (bi != bj) {
#pragma unroll
    for (int i = 0; i < 4; ++i) {
      int lin = i * 1024 + tid * 4;
      int r = lin >> 6, c = lin & 63;
      bf16x4 vb = __builtin_nontemporal_load(
          (const bf16x4*)(tb + (size_t)(bj * 64 + r) * 4096 + bi * 64 + c));
      tc[r][c] = (float)vb[0]; tc[r][c+1] = (float)vb[1];
      tc[r][c+2] = (float)vb[2]; tc[r][c+3] = (float)vb[3];
    }
  }
  __syncthreads();
#pragma unroll
  for (int i = 0; i < 4; ++i) {
    int lin = i * 1024 + tid * 4;
    int r = lin >> 6, c = lin & 63;
    int gi = bi * 64 + r, gj = bj * 64 + c;
    const float mi_ = mean[gi], ri_ = rstd[gi];
    f32x4 mj = *(const f32x4*)(mean + gj);
    f32x4 rj = *(const f32x4*)(rstd + gj);
    f32x4 o;
#pragma unroll
    for (int q = 0; q < 4; ++q) {
      float v = (ta[r][c + q] - mi_) * ri_;
      float w = (bi == bj) ? (ta[c + q][r] - mj[q]) * rj[q]
                           : (tc[c + q][r] - mj[q]) * rj[q];
      o[q] = v + w;
    }
    __builtin_nontemporal_store(o, (f32x4*)(upd + (size_t)gi * 4096 + gj));
  }
  if (bi != bj) {
#pragma unroll
    for (int i = 0; i < 4; ++i) {
      int lin = i * 1024 + tid * 4;
      int r = lin >> 6, c = lin & 63;
      int gi = bj * 64 + r, gj = bi * 64 + c;
      const float mi_ = mean[gi], ri_ = rstd[gi];
      f32x4 mj = *(const f32x4*)(mean + gj);
      f32x4 rj = *(const f32x4*)(rstd + gj);
      f32x4 o;
#pragma unroll
      for (int q = 0; q < 4; ++q) {
        float v = (tc[r][c + q] - mi_) * ri_;
        float w = (ta[c + q][r] - mj[q]) * rj[q];
        o[q] = v + w;
      }
      __builtin_nontemporal_store(o, (f32x4*)(upd + (size_t)gi * 4096 + gj));
    }
  }
}

// fallback (no-aux path): in-place f32 t -> upd, as before.
__global__ __launch_bounds__(256) void finalize_f32_kernel(
    float* __restrict__ t, const float* __restrict__ mean,
    const float* __restrict__ rstd)
{
  const int bj = blockIdx.x, bi = blockIdx.y;
  if (bi > bj) return;
  __shared__ float ta[64][65];
  __shared__ float tc[64][65];
  const int tid = threadIdx.x;
#pragma unroll
  for (int i = 0; i < 4; ++i) {
    int lin = i * 1024 + tid * 4;
    int r = lin >> 6, c = lin & 63;
    f32x4 va = *(const f32x4*)(t + (size_t)(bi * 64 + r) * 4096 + bj * 64 + c);
    ta[r][c] = va[0]; ta[r][c+1] = va[1]; ta[r][c+2] = va[2]; ta[r][c+3] = va[3];
  }
  if (bi != bj) {
#pragma unroll
    for (int i = 0; i < 4; ++i) {
      int lin = i * 1024 + tid * 4;
      int r = lin >> 6, c = lin & 63;
      f32x4 vb = *(const f32x4*)(t + (size_t)(bj * 64 + r) * 4096 + bi * 64 + c);
      tc[r][c] = vb[0]; tc[r][c+1] = vb[1]; tc[r][c+2] = vb[2]; tc[r][c+3] = vb[3];
    }
  }
  __syncthreads();
#pragma unroll
  for (int i = 0; i < 4; ++i) {
    int lin = i * 1024 + tid * 4;
    int r = lin >> 6, c = lin & 63;
    int gi = bi * 64 + r, gj = bj * 64 + c;
    const float mi_ = mean[gi], ri_ = rstd[gi];
    f32x4 mj = *(const f32x4*)(mean + gj);
    f32x4 rj = *(const f32x4*)(rstd + gj);
    f32x4 o;
#pragma unroll
    for (int q = 0; q < 4; ++q) {
      float v = (ta[r][c + q] - mi_) * ri_;
      float w = (bi == bj) ? (ta[c + q][r] - mj[q]) * rj[q]
                           : (tc[c + q][r] - mj[q]) * rj[q];
      o[q] = v + w;
    }
    *(f32x4*)(t + (size_t)gi * 4096 + gj) = o;
  }
  if (bi != bj) {
#pragma unroll
    for (int i = 0; i < 4; ++i) {
      int lin = i * 1024 + tid * 4;
      int r = lin >> 6, c = lin & 63;
      int gi = bj * 64 + r, gj = bi * 64 + c;
      const float mi_ = mean[gi], ri_ = rstd[gi];
      f32x4 mj = *(const f32x4*)(mean + gj);
      f32x4 rj = *(const f32x4*)(rstd + gj);
      f32x4 o;
#pragma unroll
      for (int q = 0; q < 4; ++q) {
        float v = (tc[r][c + q] - mi_) * ri_;
        float w = (ta[c + q][r] - mj[q]) * rj[q];
        o[q] = v + w;
      }
      *(f32x4*)(t + (size_t)gi * 4096 + gj) = o;
    }
  }
}

extern "C" void kernel_launch(void* const* d_in, const int* in_sizes, int n_in,
                              void* d_out, int out_size, void* d_ws, size_t ws_size,
                              hipStream_t stream) {
  const float* nodes  = (const float*)d_in[0];
  const float* degree = (const float*)d_in[1];
  const float* dist   = (const float*)d_in[2];
  const float* bond   = (const float*)d_in[3];
  const float* W      = (const float*)d_in[4];
  const float* a_src  = (const float*)d_in[5];
  const float* a_tgt  = (const float*)d_in[6];
  const float* w_dist = (const float*)d_in[7];
  const float* w_bond = (const float*)d_in[8];

  char* ws = (char*)d_ws;
  __bf16* nodesB = (__bf16*)ws;                                  // 2 MB
  __bf16* Wt     = (__bf16*)(ws + (2u << 20));                   // 128 KB
  __bf16* projT  = (__bf16*)(ws + (2u << 20) + (256u << 10));    // 2 MB
  __bf16* E      = (__bf16*)(ws + (9u << 20));                   // 2 MB
  float*  ssrc   = (float*)(ws + (11u << 20));                   // 16 KB
  float*  stgt   = ssrc + 4096;
  float*  mean   = stgt + 4096;
  float*  rstd   = mean + 4096;
  float*  Lrow   = rstd + 4096;                                  // 16 KB

  // aux (32 MB at +12 MB; becomes bf16 t in place) + Bsum/Bsq at +44 MB.
  const bool useAux = ws_size >= (size_t)(48u << 20);
  __bf16* aux  = useAux ? (__bf16*)(ws + (12u << 20)) : nullptr;
  float* Bsum  = useAux ? (float*)(ws + (44u << 20))
                        : (float*)(ws + (12u << 20));
  float* Bsq   = Bsum + (size_t)64 * 4096;

  float*  out0 = (float*)d_out;                 // 4096*256 f32 (output 0)
  float*  t    = out0 + (size_t)4096 * 256;     // 4096*4096 f32 (output 1 region)
  __bf16* P    = (__bf16*)t;                    // exp-scores bf16: lower 32 MiB
  __bf16* partials = (__bf16*)((char*)t + ((size_t)32 << 20)); // 8 x 2 MB bf16

  prep_kernel<<<1280, 256, 0, stream>>>(nodes, nodesB, W, Wt, Lrow, ssrc, stgt);

  // proj GEMM -> projT bf16 + fused s_src/s_tgt (atomics into ssrc/stgt)
  gemm_bf16_kernel<64, 64, 0><<<dim3(64, 4), 256, 0, stream>>>(
      nodesB, Wt, 4096, 256, 256, nullptr, projT,
      a_src, a_tgt, nullptr, nullptr, ssrc, stgt);

  // P = exp(scores), aux, Lrow — single-pass NT-load streaming map
  score_exp_kernel<<<16384, 256, 0, stream>>>(dist, bond, degree, ssrc, stgt,
                                              w_dist, w_bond, P, aux, Lrow);

  // agg-partials (bf16) = P @ projT, split-K over 8 chunks of 512
  gemm_splitk_kernel<<<dim3(64, 2, 8), 256, 0, stream>>>(P, projT, partials);

  // sum partials, /Lrow, elu -> out0 (f32, transposed, NT) + E (bf16)
  reduce_elu_kernel<<<dim3(64, 4), 256, 0, stream>>>(partials, Lrow, out0, E);

  // sim = E @ E^T -> t, + fused row stats
  if (useAux) {
    // t = bf16(sigmoid(sim)*aux + 1e-6) written IN PLACE over aux
    gemm_bf16_kernel<128, 128, 3><<<dim3(32, 32), 256, 0, stream>>>(
        E, E, 4096, 4096, 256, nullptr, nullptr,
        nullptr, nullptr, aux, nullptr, Bsum, Bsq);
    stats_small_kernel<<<16, 256, 0, stream>>>(Bsum, Bsq, mean, rstd);
    finalize_bf16_kernel<<<dim3(64, 64), 256, 0, stream>>>(aux, t, mean, rstd);
  } else {
    gemm_bf16_kernel<128, 128, 2><<<dim3(32, 32), 256, 0, stream>>>(
        E, E, 4096, 4096, 256, nullptr, nullptr,
        dist, degree, nullptr, t, Bsum, Bsq);
    stats_small_kernel<<<16, 256, 0, stream>>>(Bsum, Bsq, mean, rstd);
    finalize_f32_kernel<<<dim3(64, 64), 256, 0, stream>>>(t, mean, rstd);
  }
}

// Round 13
// 173.329 us; speedup vs baseline: 1.0828x; 1.0357x over previous
//
#include <hip/hip_runtime.h>

// GAT layer, N=4096, FIN=FOUT=256, H=1.
// prep (Wt + zero Lrow/ssrc/stgt) -> proj GEMM (reads f32 nodes NT directly,
// cvt in staging; projT bf16 + FUSED s_src/s_tgt atomics) -> score_exp
// (single-pass NT-load map + in-wave rowsum atomics; P bf16, aux bf16) ->
// split-K GEMM P@projT (BN=256, P read ONCE, bf16 partials) -> reduce (NT
// partials, /Lrow, elu -> out0 NT + E) -> sim GEMM (E E^T): epilogue reads
// aux[idx] NT, overwrites IN PLACE with t=bf16(sigmoid*aux+1e-6) + fused row
// stats -> stats_small -> finalize (NT bf16 t reads, NT f32 upd stores).

using f32x4  = __attribute__((ext_vector_type(4))) float;
using bf16x8 = __attribute__((ext_vector_type(8))) __bf16;
using bf16x4 = __attribute__((ext_vector_type(4))) __bf16;
using u32x4  = __attribute__((ext_vector_type(4))) unsigned int;

// grid 256: Wt transpose + zero Lrow/ssrc/stgt
__global__ __launch_bounds__(256) void prep_kernel(const float* __restrict__ w,
                                                   __bf16* __restrict__ wt,
                                                   float* __restrict__ Lrow,
                                                   float* __restrict__ ssrc,
                                                   float* __restrict__ stgt) {
  const int bx = blockIdx.x;
  int i = bx * 256 + threadIdx.x;
  int o = i >> 8, f = i & 255;
  wt[i] = (__bf16)w[f * 256 + o];
  if (bx < 16)       Lrow[bx * 256 + threadIdx.x] = 0.0f;
  else if (bx < 32)  ssrc[(bx - 16) * 256 + threadIdx.x] = 0.0f;
  else if (bx < 48)  stgt[(bx - 32) * 256 + threadIdx.x] = 0.0f;
}

// proj GEMM: reads f32 nodes (NT) directly, BM=64 BN=128, 512 thr (8 waves,
// 2m x 4n, NI=2). projT bf16 [n*4096+m]; fused s_src/s_tgt row-dots -> atomics.
__global__ __launch_bounds__(512) void proj_gemm_kernel(
    const float* __restrict__ nodes, const __bf16* __restrict__ Wt,
    __bf16* __restrict__ projT, const float* __restrict__ asrc,
    const float* __restrict__ atgt, float* __restrict__ ssrc,
    float* __restrict__ stgt)
{
  constexpr int LDT = 72;
  __shared__ alignas(16) __bf16 As[64 * LDT];
  __shared__ alignas(16) __bf16 Bs[128 * LDT];
  const int tid  = threadIdx.x;
  const int lane = tid & 63;
  const int wid  = tid >> 6;
  const int wm0  = (wid >> 2) * 32;
  const int wn0  = (wid & 3) * 32;
  const int m0   = blockIdx.x * 64;
  const int n0   = blockIdx.y * 128;
  const int lr   = lane & 15;
  const int lk   = lane >> 4;
  const int r    = tid >> 3;           // A row (0..63)
  const int c0   = (tid & 7) * 8;      // A col base within k-step

  f32x4 acc[2][2];
#pragma unroll
  for (int a = 0; a < 2; ++a)
#pragma unroll
    for (int b = 0; b < 2; ++b) acc[a][b] = (f32x4){0.f, 0.f, 0.f, 0.f};

#pragma unroll
  for (int it = 0; it < 4; ++it) {
    const int kt = it * 64;
    f32x4 a0 = __builtin_nontemporal_load(
        (const f32x4*)(nodes + (size_t)(m0 + r) * 256 + kt + c0));
    f32x4 a1 = __builtin_nontemporal_load(
        (const f32x4*)(nodes + (size_t)(m0 + r) * 256 + kt + c0 + 4));
    u32x4 bl[2];
#pragma unroll
    for (int i = 0; i < 2; ++i) {
      int idx = i * 512 + tid;
      int nB = idx >> 3, cB = idx & 7;
      bl[i] = *(const u32x4*)(Wt + (size_t)(n0 + nB) * 256 + kt + cB * 8);
    }
    __syncthreads();   // previous MFMA done reading LDS
    bf16x8 ab = { (__bf16)a0[0], (__bf16)a0[1], (__bf16)a0[2], (__bf16)a0[3],
                  (__bf16)a1[0], (__bf16)a1[1], (__bf16)a1[2], (__bf16)a1[3] };
    *(bf16x8*)(As + r * LDT + c0) = ab;
#pragma unroll
    for (int i = 0; i < 2; ++i) {
      int idx = i * 512 + tid;
      int nB = idx >> 3, cB = idx & 7;
      *(u32x4*)(Bs + nB * LDT + cB * 8) = bl[i];
    }
    __syncthreads();
#pragma unroll
    for (int kk = 0; kk < 2; ++kk) {
      bf16x8 av[2], bv[2];
#pragma unroll
      for (int mi = 0; mi < 2; ++mi)
        av[mi] = *(const bf16x8*)(As + (wm0 + mi * 16 + lr) * LDT + kk * 32 + lk * 8);
#pragma unroll
      for (int ni = 0; ni < 2; ++ni)
        bv[ni] = *(const bf16x8*)(Bs + (wn0 + ni * 16 + lr) * LDT + kk * 32 + lk * 8);
#pragma unroll
      for (int mi = 0; mi < 2; ++mi)
#pragma unroll
        for (int ni = 0; ni < 2; ++ni)
          acc[mi][ni] = __builtin_amdgcn_mfma_f32_16x16x32_bf16(av[mi], bv[ni], acc[mi][ni], 0, 0, 0);
    }
  }

#pragma unroll
  for (int mi = 0; mi < 2; ++mi) {
#pragma unroll
    for (int j = 0; j < 4; ++j) {
      const int m = m0 + wm0 + mi * 16 + lk * 4 + j;
      float s1 = 0.f, s2 = 0.f;
#pragma unroll
      for (int ni = 0; ni < 2; ++ni) {
        const int n = n0 + wn0 + ni * 16 + lr;
        const float v = acc[mi][ni][j];
        projT[(size_t)n * 4096 + m] = (__bf16)v;
        s1 += v * asrc[n];
        s2 += v * atgt[n];
      }
#pragma unroll
      for (int o = 1; o < 16; o <<= 1) {
        s1 += __shfl_xor(s1, o, 64);
        s2 += __shfl_xor(s2, o, 64);
      }
      if (lr == 0) {
        atomicAdd(ssrc + m, s1);
        atomicAdd(stgt + m, s2);
      }
    }
  }
}

// sim GEMM: C[m,n] = sum_k A[m,k]*Bt[n,k], BM=BN=128.
// MODE 2: t(f32) = sigmoid(v)*(-e0)*(e1>0)+1e-6            (+ fused row stats)
// MODE 3: axt[idx] <- bf16(sigmoid(v)*NT(axt[idx])+1e-6)   in-place (+ stats)
template<int MODE>
__global__ __launch_bounds__(256) void sim_gemm_kernel(
    const __bf16* __restrict__ A, const __bf16* __restrict__ Bt, int K,
    const float* __restrict__ e0, const float* __restrict__ e1,
    __bf16* __restrict__ axt, float* __restrict__ outt,
    float* __restrict__ bsum, float* __restrict__ bsq)
{
  constexpr int LDT = 72;
  __shared__ alignas(16) __bf16 As[128 * LDT];
  __shared__ alignas(16) __bf16 Bs[128 * LDT];
  const int tid  = threadIdx.x;
  const int lane = tid & 63;
  const int wid  = tid >> 6;
  const int wm0  = (wid >> 1) * 64;
  const int wn0  = (wid & 1) * 64;
  const int m0   = blockIdx.x * 128;
  const int n0   = blockIdx.y * 128;
  const int lr   = lane & 15;
  const int lk   = lane >> 4;

  f32x4 acc[4][4];
#pragma unroll
  for (int a = 0; a < 4; ++a)
#pragma unroll
    for (int b = 0; b < 4; ++b) acc[a][b] = (f32x4){0.f, 0.f, 0.f, 0.f};

  for (int kt = 0; kt < K; kt += 64) {
    __syncthreads();
    for (int idx = tid; idx < 1024; idx += 256) {
      int r = idx >> 3, c = idx & 7;
      u32x4 v = *(const u32x4*)(A + (size_t)(m0 + r) * K + kt + c * 8);
      *(u32x4*)(As + r * LDT + c * 8) = v;
    }
    for (int idx = tid; idx < 1024; idx += 256) {
      int r = idx >> 3, c = idx & 7;
      u32x4 v = *(const u32x4*)(Bt + (size_t)(n0 + r) * K + kt + c * 8);
      *(u32x4*)(Bs + r * LDT + c * 8) = v;
    }
    __syncthreads();
#pragma unroll
    for (int kk = 0; kk < 2; ++kk) {
      bf16x8 av[4], bv[4];
#pragma unroll
      for (int mi = 0; mi < 4; ++mi)
        av[mi] = *(const bf16x8*)(As + (wm0 + mi * 16 + lr) * LDT + kk * 32 + lk * 8);
#pragma unroll
      for (int ni = 0; ni < 4; ++ni)
        bv[ni] = *(const bf16x8*)(Bs + (wn0 + ni * 16 + lr) * LDT + kk * 32 + lk * 8);
#pragma unroll
      for (int mi = 0; mi < 4; ++mi)
#pragma unroll
        for (int ni = 0; ni < 4; ++ni)
          acc[mi][ni] = __builtin_amdgcn_mfma_f32_16x16x32_bf16(av[mi], bv[ni], acc[mi][ni], 0, 0, 0);
    }
  }

#pragma unroll
  for (int mi = 0; mi < 4; ++mi) {
#pragma unroll
    for (int j = 0; j < 4; ++j) {
      const int m = m0 + wm0 + mi * 16 + lk * 4 + j;
      float s = 0.f, s2 = 0.f;
#pragma unroll
      for (int ni = 0; ni < 4; ++ni) {
        const int n = n0 + wn0 + ni * 16 + lr;
        const size_t idx = (size_t)m * 4096 + n;
        const float v = acc[mi][ni][j];
        const float sg = 1.0f / (1.0f + __expf(-v));
        float tr;
        if constexpr (MODE == 2) {
          const float d = e0[idx];
          const float g = e1[idx];
          const float tval = sg * (-d) * (g > 0.f ? 1.0f : 0.0f) + 1e-6f;
          outt[idx] = tval;
          tr = tval;
        } else {
          const float a = (float)__builtin_nontemporal_load(axt + idx);
          const __bf16 tb = (__bf16)(sg * a + 1e-6f);
          axt[idx] = tb;               // in-place: aux -> t (bf16)
          tr = (float)tb;              // stats on the rounded value
        }
        s += tr;
        s2 += tr * tr;
      }
#pragma unroll
      for (int o = 1; o < 16; o <<= 1) {
        s  += __shfl_xor(s, o, 64);
        s2 += __shfl_xor(s2, o, 64);
      }
      if (lr == 0) {
        const int slot = blockIdx.y * 2 + (wid & 1);   // 64 col-slots
        bsum[(size_t)slot * 4096 + m] = s;
        bsq [(size_t)slot * 4096 + m] = s2;
      }
    }
  }
}

// mean/rstd from 64 column-block partial sums. grid 16 x 256.
__global__ __launch_bounds__(256) void stats_small_kernel(
    const float* __restrict__ bsum, const float* __restrict__ bsq,
    float* __restrict__ mean, float* __restrict__ rstd)
{
  const int row = blockIdx.x * 256 + threadIdx.x;
  float S = 0.f, S2 = 0.f;
#pragma unroll 8
  for (int s = 0; s < 64; ++s) {
    S  += bsum[(size_t)s * 4096 + row];
    S2 += bsq [(size_t)s * 4096 + row];
  }
  const float m  = S * (1.0f / 4096.0f);
  const float var = S2 * (1.0f / 4096.0f) - m * m;
  mean[row] = m;
  rstd[row] = rsqrtf(var + 1e-5f);
}

// Single-pass NT-load streaming map + in-wave rowsum atomics.
__global__ __launch_bounds__(256) void score_exp_kernel(
    const float* __restrict__ dist, const float* __restrict__ bond,
    const float* __restrict__ deg,  const float* __restrict__ ssrc,
    const float* __restrict__ stgt, const float* __restrict__ wdp,
    const float* __restrict__ wbp,  __bf16* __restrict__ P,
    __bf16* __restrict__ aux,       float* __restrict__ Lrow)
{
  const float wd = wdp[0], wb = wbp[0];
  const int lane = threadIdx.x & 63;
  const size_t i = ((size_t)blockIdx.x * 256 + threadIdx.x) * 4;
  const int row = (int)(i >> 12);
  const int col = (int)(i & 4095);
  f32x4 d  = __builtin_nontemporal_load((const f32x4*)(dist + i));
  f32x4 g  = __builtin_nontemporal_load((const f32x4*)(deg + i));
  f32x4 b  = __builtin_nontemporal_load((const f32x4*)(bond + i));
  f32x4 st = *(const f32x4*)(stgt + col);
  const float si = ssrc[row];
  f32x4 p;
  bf16x4 pb, ab;
#pragma unroll
  for (int q = 0; q < 4; ++q) {
    float x = si + st[q];
    x = x > 0.f ? x : 0.2f * x;
    x += -d[q] * wd + b[q] * wb + (g[q] > 0.f ? g[q] : -1000000.0f);
    p[q] = __expf(x);
    pb[q] = (__bf16)p[q];
    ab[q] = (__bf16)(g[q] > 0.f ? -d[q] : 0.0f);
  }
  *(bf16x4*)(P + i) = pb;
  if (aux) *(bf16x4*)(aux + i) = ab;
  float s = p[0] + p[1] + p[2] + p[3];
#pragma unroll
  for (int o = 32; o; o >>= 1) s += __shfl_xor(s, o, 64);
  if (lane == 0) atomicAdd(Lrow + row, s);   // whole wave is in one row
}

// split-K GEMM: partial[s][m*256+n] (bf16), BM=64 BN=256 (P read ONCE),
// K-chunk 512. grid (64, 8), 512 threads (8 waves, 2m x 4n).
__global__ __launch_bounds__(512) void gemm_splitk_kernel(
    const __bf16* __restrict__ A, const __bf16* __restrict__ Bt,
    __bf16* __restrict__ partial)
{
  constexpr int LDT = 72;
  __shared__ alignas(16) __bf16 As[64 * LDT];
  __shared__ alignas(16) __bf16 Bs[256 * LDT];
  const int tid  = threadIdx.x;
  const int lane = tid & 63;
  const int wid  = tid >> 6;
  const int wm0  = (wid >> 2) * 32;
  const int wn0  = (wid & 3) * 64;
  const int m0   = blockIdx.x * 64;
  const int s    = blockIdx.y;
  const int lr   = lane & 15;
  const int lk   = lane >> 4;
  const int rA   = tid >> 3, cA = tid & 7;

  f32x4 acc[2][4];
#pragma unroll
  for (int a = 0; a < 2; ++a)
#pragma unroll
    for (int b = 0; b < 4; ++b) acc[a][b] = (f32x4){0.f, 0.f, 0.f, 0.f};

  const int k0 = s * 512;
  for (int kt = k0; kt < k0 + 512; kt += 64) {
    u32x4 va = *(const u32x4*)(A + (size_t)(m0 + rA) * 4096 + kt + cA * 8);
    u32x4 vb[4];
#pragma unroll
    for (int i = 0; i < 4; ++i) {
      int idx = i * 512 + tid;
      int rB = idx >> 3, cB = idx & 7;
      vb[i] = *(const u32x4*)(Bt + (size_t)rB * 4096 + kt + cB * 8);
    }
    __syncthreads();   // previous MFMA done reading LDS
    *(u32x4*)(As + rA * LDT + cA * 8) = va;
#pragma unroll
    for (int i = 0; i < 4; ++i) {
      int idx = i * 512 + tid;
      int rB = idx >> 3, cB = idx & 7;
      *(u32x4*)(Bs + rB * LDT + cB * 8) = vb[i];
    }
    __syncthreads();
#pragma unroll
    for (int kk = 0; kk < 2; ++kk) {
      bf16x8 av[2], bv[4];
#pragma unroll
      for (int mi = 0; mi < 2; ++mi)
        av[mi] = *(const bf16x8*)(As + (wm0 + mi * 16 + lr) * LDT + kk * 32 + lk * 8);
#pragma unroll
      for (int ni = 0; ni < 4; ++ni)
        bv[ni] = *(const bf16x8*)(Bs + (wn0 + ni * 16 + lr) * LDT + kk * 32 + lk * 8);
#pragma unroll
      for (int mi = 0; mi < 2; ++mi)
#pragma unroll
        for (int ni = 0; ni < 4; ++ni)
          acc[mi][ni] = __builtin_amdgcn_mfma_f32_16x16x32_bf16(av[mi], bv[ni], acc[mi][ni], 0, 0, 0);
    }
  }

  __bf16* Pp = partial + (size_t)s * (4096 * 256);
#pragma unroll
  for (int mi = 0; mi < 2; ++mi)
#pragma unroll
    for (int ni = 0; ni < 4; ++ni)
#pragma unroll
      for (int j = 0; j < 4; ++j) {
        const int m = m0 + wm0 + mi * 16 + lk * 4 + j;
        const int n = wn0 + ni * 16 + lr;
        Pp[(size_t)m * 256 + n] = (__bf16)acc[mi][ni][j];
      }
}

// sum 8 bf16 partials (NT), /Lrow, elu -> out0 (NT store) + E (bf16).
__global__ __launch_bounds__(256) void reduce_elu_kernel(
    const __bf16* __restrict__ partial, const float* __restrict__ Lrow,
    float* __restrict__ out0, __bf16* __restrict__ E)
{
  __shared__ float tile[64][65];
  __shared__ float invL[64];
  const int tid = threadIdx.x;
  const int m0 = blockIdx.x * 64;
  const int f0 = blockIdx.y * 64;
  if (tid < 64) invL[tid] = 1.0f / Lrow[m0 + tid];
  f32x4 accv[4];
#pragma unroll
  for (int i = 0; i < 4; ++i) {
    int lin = i * 1024 + tid * 4;
    int r = lin >> 6, c = lin & 63;
    f32x4 sum = (f32x4){0.f, 0.f, 0.f, 0.f};
#pragma unroll
    for (int s = 0; s < 8; ++s) {
      bf16x4 pv = __builtin_nontemporal_load(
          (const bf16x4*)(partial + (size_t)s * (4096 * 256) +
                          (size_t)(m0 + r) * 256 + f0 + c));
#pragma unroll
      for (int q = 0; q < 4; ++q) sum[q] += (float)pv[q];
    }
    accv[i] = sum;
  }
  __syncthreads();   // invL ready
#pragma unroll
  for (int i = 0; i < 4; ++i) {
    int lin = i * 1024 + tid * 4;
    int r = lin >> 6, c = lin & 63;
    const float inv = invL[r];
    tile[r][c]     = accv[i][0] * inv;
    tile[r][c + 1] = accv[i][1] * inv;
    tile[r][c + 2] = accv[i][2] * inv;
    tile[r][c + 3] = accv[i][3] * inv;
  }
  __syncthreads();
#pragma unroll
  for (int i = 0; i < 4; ++i) {
    int lin = i * 1024 + tid * 4;
    int rr = lin >> 6, cc = lin & 63;   // rr: feature offset, cc: node offset
    f32x4 e;
#pragma unroll
    for (int q = 0; q < 4; ++q) {
      float v = tile[cc + q][rr];
      e[q] = v > 0.f ? v : expm1f(v);
    }
    size_t idx = (size_t)(f0 + rr) * 4096 + m0 + cc;
    __builtin_nontemporal_store(e, (f32x4*)(out0 + idx));
    bf16x4 eb = { (__bf16)e[0], (__bf16)e[1], (__bf16)e[2], (__bf16)e[3] };
    *(bf16x4*)(E + idx) = eb;
  }
}

// upd[i,j] = (t[i,j]-mean_i)*rstd_i + (t[j,i]-mean_j)*rstd_j
__global__ __launch_bounds__(256) void finalize_bf16_kernel(
    const __bf16* __restrict__ tb, float* __restrict__ upd,
    const float* __restrict__ mean, const float* __restrict__ rstd)
{
  const int bj = blockIdx.x, bi = blockIdx.y;
  if (bi > bj) return;
  __shared__ float ta[64][65];
  __shared__ float tc[64][65];
  const int tid = threadIdx.x;
#pragma unroll
  for (int i = 0; i < 4; ++i) {
    int lin = i * 1024 + tid * 4;
    int r = lin >> 6, c = lin & 63;
    bf16x4 va = __builtin_nontemporal_load(
        (const bf16x4*)(tb + (size_t)(bi * 64 + r) * 4096 + bj * 64 + c));
    ta[r][c] = (float)va[0]; ta[r][c+1] = (float)va[1];
    ta[r][c+2] = (float)va[2]; ta[r][c+3] = (float)va[3];
  }
  if (bi != bj) {
#pragma unroll
    for (int i = 0; i < 4; ++i) {
      int lin = i * 1024 + tid * 4;
      int r = lin >> 6, c = lin & 63;
      bf16x4 vb = __builtin_nontemporal_load(
          (const bf16x4*)(tb + (size_t)(bj * 64 + r) * 4096 + bi * 64 + c));
      tc[r][c] = (float)vb[0]; tc[r][c+1] = (float)vb[1];
      tc[r][c+2] = (float)vb[2]; tc[r][c+3] = (float)vb[3];
    }
  }
  __syncthreads();
#pragma unroll
  for (int i = 0; i < 4; ++i) {
    int lin = i * 1024 + tid * 4;
    int r = lin >> 6, c = lin & 63;
    int gi = bi * 64 + r, gj = bj * 64 + c;
    const float mi_ = mean[gi], ri_ = rstd[gi];
    f32x4 mj = *(const f32x4*)(mean + gj);
    f32x4 rj = *(const f32x4*)(rstd + gj);
    f32x4 o;
#pragma unroll
    for (int q = 0; q < 4; ++q) {
      float v = (ta[r][c + q] - mi_) * ri_;
      float w = (bi == bj) ? (ta[c + q][r] - mj[q]) * rj[q]
                           : (tc[c + q][r] - mj[q]) * rj[q];
      o[q] = v + w;
    }
    __builtin_nontemporal_store(o, (f32x4*)(upd + (size_t)gi * 4096 + gj));
  }
  if (bi != bj) {
#pragma unroll
    for (int i = 0; i < 4; ++i) {
      int lin = i * 1024 + tid * 4;
      int r = lin >> 6, c = lin & 63;
      int gi = bj * 64 + r, gj = bi * 64 + c;
      const float mi_ = mean[gi], ri_ = rstd[gi];
      f32x4 mj = *(const f32x4*)(mean + gj);
      f32x4 rj = *(const f32x4*)(rstd + gj);
      f32x4 o;
#pragma unroll
      for (int q = 0; q < 4; ++q) {
        float v = (tc[r][c + q] - mi_) * ri_;
        float w = (ta[c + q][r] - mj[q]) * rj[q];
        o[q] = v + w;
      }
      __builtin_nontemporal_store(o, (f32x4*)(upd + (size_t)gi * 4096 + gj));
    }
  }
}

// fallback (no-aux path): in-place f32 t -> upd.
__global__ __launch_bounds__(256) void finalize_f32_kernel(
    float* __restrict__ t, const float* __restrict__ mean,
    const float* __restrict__ rstd)
{
  const int bj = blockIdx.x, bi = blockIdx.y;
  if (bi > bj) return;
  __shared__ float ta[64][65];
  __shared__ float tc[64][65];
  const int tid = threadIdx.x;
#pragma unroll
  for (int i = 0; i < 4; ++i) {
    int lin = i * 1024 + tid * 4;
    int r = lin >> 6, c = lin & 63;
    f32x4 va = *(const f32x4*)(t + (size_t)(bi * 64 + r) * 4096 + bj * 64 + c);
    ta[r][c] = va[0]; ta[r][c+1] = va[1]; ta[r][c+2] = va[2]; ta[r][c+3] = va[3];
  }
  if (bi != bj) {
#pragma unroll
    for (int i = 0; i < 4; ++i) {
      int lin = i * 1024 + tid * 4;
      int r = lin >> 6, c = lin & 63;
      f32x4 vb = *(const f32x4*)(t + (size_t)(bj * 64 + r) * 4096 + bi * 64 + c);
      tc[r][c] = vb[0]; tc[r][c+1] = vb[1]; tc[r][c+2] = vb[2]; tc[r][c+3] = vb[3];
    }
  }
  __syncthreads();
#pragma unroll
  for (int i = 0; i < 4; ++i) {
    int lin = i * 1024 + tid * 4;
    int r = lin >> 6, c = lin & 63;
    int gi = bi * 64 + r, gj = bj * 64 + c;
    const float mi_ = mean[gi], ri_ = rstd[gi];
    f32x4 mj = *(const f32x4*)(mean + gj);
    f32x4 rj = *(const f32x4*)(rstd + gj);
    f32x4 o;
#pragma unroll
    for (int q = 0; q < 4; ++q) {
      float v = (ta[r][c + q] - mi_) * ri_;
      float w = (bi == bj) ? (ta[c + q][r] - mj[q]) * rj[q]
                           : (tc[c + q][r] - mj[q]) * rj[q];
      o[q] = v + w;
    }
    *(f32x4*)(t + (size_t)gi * 4096 + gj) = o;
  }
  if (bi != bj) {
#pragma unroll
    for (int i = 0; i < 4; ++i) {
      int lin = i * 1024 + tid * 4;
      int r = lin >> 6, c = lin & 63;
      int gi = bj * 64 + r, gj = bi * 64 + c;
      const float mi_ = mean[gi], ri_ = rstd[gi];
      f32x4 mj = *(const f32x4*)(mean + gj);
      f32x4 rj = *(const f32x4*)(rstd + gj);
      f32x4 o;
#pragma unroll
      for (int q = 0; q < 4; ++q) {
        float v = (tc[r][c + q] - mi_) * ri_;
        float w = (ta[c + q][r] - mj[q]) * rj[q];
        o[q] = v + w;
      }
      *(f32x4*)(t + (size_t)gi * 4096 + gj) = o;
    }
  }
}

extern "C" void kernel_launch(void* const* d_in, const int* in_sizes, int n_in,
                              void* d_out, int out_size, void* d_ws, size_t ws_size,
                              hipStream_t stream) {
  const float* nodes  = (const float*)d_in[0];
  const float* degree = (const float*)d_in[1];
  const float* dist   = (const float*)d_in[2];
  const float* bond   = (const float*)d_in[3];
  const float* W      = (const float*)d_in[4];
  const float* a_src  = (const float*)d_in[5];
  const float* a_tgt  = (const float*)d_in[6];
  const float* w_dist = (const float*)d_in[7];
  const float* w_bond = (const float*)d_in[8];

  char* ws = (char*)d_ws;
  __bf16* Wt     = (__bf16*)(ws + (2u << 20));                   // 128 KB
  __bf16* projT  = (__bf16*)(ws + (2u << 20) + (256u << 10));    // 2 MB
  __bf16* E      = (__bf16*)(ws + (9u << 20));                   // 2 MB
  float*  ssrc   = (float*)(ws + (11u << 20));                   // 16 KB
  float*  stgt   = ssrc + 4096;
  float*  mean   = stgt + 4096;
  float*  rstd   = mean + 4096;
  float*  Lrow   = rstd + 4096;                                  // 16 KB

  // aux (32 MB at +12 MB; becomes bf16 t in place) + Bsum/Bsq at +44 MB.
  const bool useAux = ws_size >= (size_t)(48u << 20);
  __bf16* aux  = useAux ? (__bf16*)(ws + (12u << 20)) : nullptr;
  float* Bsum  = useAux ? (float*)(ws + (44u << 20))
                        : (float*)(ws + (12u << 20));
  float* Bsq   = Bsum + (size_t)64 * 4096;

  float*  out0 = (float*)d_out;                 // 4096*256 f32 (output 0)
  float*  t    = out0 + (size_t)4096 * 256;     // 4096*4096 f32 (output 1 region)
  __bf16* P    = (__bf16*)t;                    // exp-scores bf16: lower 32 MiB
  __bf16* partials = (__bf16*)((char*)t + ((size_t)32 << 20)); // 8 x 2 MB bf16

  prep_kernel<<<256, 256, 0, stream>>>(W, Wt, Lrow, ssrc, stgt);

  // proj GEMM (f32 nodes NT -> bf16 in staging) + fused s_src/s_tgt atomics
  proj_gemm_kernel<<<dim3(64, 2), 512, 0, stream>>>(
      nodes, Wt, projT, a_src, a_tgt, ssrc, stgt);

  // P = exp(scores), aux, Lrow — single-pass NT-load streaming map
  score_exp_kernel<<<16384, 256, 0, stream>>>(dist, bond, degree, ssrc, stgt,
                                              w_dist, w_bond, P, aux, Lrow);

  // agg-partials (bf16) = P @ projT, split-K over 8 chunks of 512, P read once
  gemm_splitk_kernel<<<dim3(64, 8), 512, 0, stream>>>(P, projT, partials);

  // sum partials, /Lrow, elu -> out0 (f32, transposed, NT) + E (bf16)
  reduce_elu_kernel<<<dim3(64, 4), 256, 0, stream>>>(partials, Lrow, out0, E);

  // sim = E @ E^T -> t, + fused row stats
  if (useAux) {
    sim_gemm_kernel<3><<<dim3(32, 32), 256, 0, stream>>>(
        E, E, 256, nullptr, nullptr, aux, nullptr, Bsum, Bsq);
    stats_small_kernel<<<16, 256, 0, stream>>>(Bsum, Bsq, mean, rstd);
    finalize_bf16_kernel<<<dim3(64, 64), 256, 0, stream>>>(aux, t, mean, rstd);
  } else {
    sim_gemm_kernel<2><<<dim3(32, 32), 256, 0, stream>>>(
        E, E, 256, dist, degree, nullptr, t, Bsum, Bsq);
    stats_small_kernel<<<16, 256, 0, stream>>>(Bsum, Bsq, mean, rstd);
    finalize_f32_kernel<<<dim3(64, 64), 256, 0, stream>>>(t, mean, rstd);
  }
}